// Round 20
// baseline (203.768 us; speedup 1.0000x reference)
//
#include <hip/hip_runtime.h>
#include <hip/hip_fp16.h>
#include <math.h>

// ---------------- problem constants ----------------
constexpr int NN   = 50000;          // nodes
constexpr int NE   = 150000;         // edges
constexpr int DIN  = 48;
constexpr int DH   = 64;
constexpr int DE   = 16;
constexpr int NHD  = 10;             // heads
constexpr int NL   = 3;              // layers
constexpr int DOUTC= 128;
constexpr int NG   = 4096;           // graphs
constexpr int E2   = NE + NN;        // edges incl self loops (200000)
constexpr int SCAN_B  = 256;
constexpr int SCAN_NB = (NN + SCAN_B - 1) / SCAN_B;   // 196

typedef __bf16 v8bf __attribute__((ext_vector_type(8)));
typedef short  v8s  __attribute__((ext_vector_type(8)));
typedef float  v4f  __attribute__((ext_vector_type(4)));

__device__ inline unsigned short f2bf(float f) {
    unsigned u = __builtin_bit_cast(unsigned, f);
    unsigned r = (u + 0x7FFFu + ((u >> 16) & 1u)) >> 16;
    return (unsigned short)r;
}

__device__ inline v4f MF(v8s a, v8s b, v4f c) {
    return __builtin_amdgcn_mfma_f32_16x16x32_bf16(
        __builtin_bit_cast(v8bf, a), __builtin_bit_cast(v8bf, b), c, 0, 0, 0);
}
__device__ inline v4f MFB(v8bf a, v8s b, v4f c) {
    return __builtin_amdgcn_mfma_f32_16x16x32_bf16(
        a, __builtin_bit_cast(v8bf, b), c, 0, 0, 0);
}

// broadcast from a compile-time lane (no LDS)
#define RLI(v, l) __builtin_amdgcn_readlane((v), (l))
#define RLH2(v, l) __builtin_bit_cast(__half2, __builtin_amdgcn_readlane(__builtin_bit_cast(int, (v)), (l)))

// ---------------- preprocessing ----------------
__global__ void k_cnt(const int* __restrict__ dst, int* __restrict__ cnt) {
    int e = blockIdx.x * blockDim.x + threadIdx.x;
    if (e < NE) atomicAdd(&cnt[dst[e]], 1);
}

// single-pass scan: each block computes its prefix offset by grid-striding cnt
// (L2-hot, ~0.5us total), then local inclusive scan; also zeroes cursor.
__global__ void k_scan(const int* __restrict__ cnt, int* __restrict__ rp,
                       int* __restrict__ cursor) {
    __shared__ int s[SCAN_B];
    __shared__ int boff_s;
    const int t = threadIdx.x;
    const int lim = blockIdx.x * SCAN_B;
    int sum = 0;
    for (int i = t; i < lim; i += SCAN_B) sum += cnt[i] + 1;
    s[t] = sum;
    __syncthreads();
    for (int off = SCAN_B / 2; off > 0; off >>= 1) {
        if (t < off) s[t] += s[t + off];
        __syncthreads();
    }
    if (t == 0) boff_s = s[0];
    __syncthreads();
    const int boff = boff_s;
    __syncthreads();
    int i = lim + t;
    if (i < NN) cursor[i] = 0;
    int v = (i < NN) ? (cnt[i] + 1) : 0;
    s[t] = v;
    __syncthreads();
    for (int off = 1; off < SCAN_B; off <<= 1) {
        int tv = (t >= off) ? s[t - off] : 0;
        __syncthreads();
        s[t] += tv;
        __syncthreads();
    }
    if (i < NN) {
        int excl = boff + s[t] - v;
        rp[i] = excl;
        if (i == NN - 1) rp[NN] = excl + v;
    }
}

__global__ void k_csr_fill(const int* __restrict__ src, const int* __restrict__ dst,
                           const int* __restrict__ rp, int* __restrict__ cursor,
                           int* __restrict__ eidx, int* __restrict__ scsr) {
    int e = blockIdx.x * blockDim.x + threadIdx.x;
    if (e >= E2) return;
    int d  = (e < NE) ? dst[e] : (e - NE);
    int sn = (e < NE) ? src[e] : d;
    int pos = atomicAdd(&cursor[d], 1);
    int s = rp[d] + pos;
    eidx[s] = e; scsr[s] = sn;
}

// merged: snl12 metadata + graph row ptrs + self-loop attrs (per-node, vectorized)
__global__ void k_misc(const int* __restrict__ rp, const int* __restrict__ scsr,
                       const int* __restrict__ eidx, const int* __restrict__ cnt,
                       const float* __restrict__ ea, const int* __restrict__ batch,
                       int* __restrict__ snl12, int* __restrict__ grp,
                       float* __restrict__ loop) {
    int tid = blockIdx.x * blockDim.x + threadIdx.x;
    if (tid < NN * 16) {
        int n = tid >> 4, j = tid & 15;
        int r0 = rp[n], deg = rp[n + 1] - r0;
        int v;
        if (j < 12)      v = (j < deg) ? scsr[r0 + j] : 0;
        else if (j == 12) v = deg;
        else if (j == 13) v = r0;
        else             v = 0;
        snl12[tid] = v;
    } else if (tid < NN * 17) {
        int n = tid - NN * 16;
        int b = batch[n];
        int pb = (n == 0) ? -1 : batch[n - 1];
        for (int g = pb + 1; g <= b; ++g) grp[g] = n;
        if (n == NN - 1) for (int g = b + 1; g <= NG; ++g) grp[g] = NN;
    } else if (tid < NN * 18) {
        int n = tid - NN * 17;
        int r0 = rp[n], r1 = rp[n + 1];
        float4 a0 = {0.f,0.f,0.f,0.f}, a1 = {0.f,0.f,0.f,0.f};
        float4 a2 = {0.f,0.f,0.f,0.f}, a3 = {0.f,0.f,0.f,0.f};
        for (int q = r0; q < r1; ++q) {
            int eid = eidx[q];
            if (eid < NE) {
                const float* ar = ea + (size_t)eid * DE;
                float4 b0 = *(const float4*)(ar + 0);
                float4 b1 = *(const float4*)(ar + 4);
                float4 b2 = *(const float4*)(ar + 8);
                float4 b3 = *(const float4*)(ar + 12);
                a0.x+=b0.x; a0.y+=b0.y; a0.z+=b0.z; a0.w+=b0.w;
                a1.x+=b1.x; a1.y+=b1.y; a1.z+=b1.z; a1.w+=b1.w;
                a2.x+=b2.x; a2.y+=b2.y; a2.z+=b2.z; a2.w+=b2.w;
                a3.x+=b3.x; a3.y+=b3.y; a3.z+=b3.z; a3.w+=b3.w;
            }
        }
        int c = cnt[n];
        float inv = (c > 1) ? (1.0f / (float)c) : 1.0f;
        a0.x*=inv; a0.y*=inv; a0.z*=inv; a0.w*=inv;
        a1.x*=inv; a1.y*=inv; a1.z*=inv; a1.w*=inv;
        a2.x*=inv; a2.y*=inv; a2.z*=inv; a2.w*=inv;
        a3.x*=inv; a3.y*=inv; a3.z*=inv; a3.w*=inv;
        float* lp = loop + (size_t)n * DE;
        *(float4*)(lp + 0)  = a0;
        *(float4*)(lp + 4)  = a1;
        *(float4*)(lp + 8)  = a2;
        *(float4*)(lp + 12) = a3;
    }
}

// ---------------- merged constant prep: BtP + WcB(direct dot) + W_emb hi/lo + WeT + cnt zero ----------------
constexpr int N_BTP = NL * 40960;      // 122880
constexpr int N_WCB = NL * 2048;       // 6144
constexpr int N_EMB = DH * 64;         // 4096
constexpr int N_WET = NL * DE * NHD;   // 480
constexpr int N_PRE = N_BTP + N_WCB + N_EMB + N_WET + NN;
__global__ void k_prep(const float* __restrict__ Ws, const float* __restrict__ asrc,
                       const float* __restrict__ adst, const float* __restrict__ We_in,
                       const float* __restrict__ aedge, const float* __restrict__ Wemb,
                       unsigned short* __restrict__ BtP, unsigned short* __restrict__ WcB,
                       unsigned short* __restrict__ BH, unsigned short* __restrict__ BL,
                       float* __restrict__ WeT, int* __restrict__ cnt) {
    int tid = blockIdx.x * blockDim.x + threadIdx.x;
    if (tid < N_BTP) {
        int e  = tid & 7;
        int ln = (tid >> 3) & 63;
        int t  = (tid >> 9) % 20;
        int ct = (tid / 10240) & 3;
        int l  = tid / 40960;
        int f = ct * 16 + (ln & 15);
        int kidx = t * 32 + (ln >> 4) * 8 + e;
        int k = kidx / 10, q = kidx - 10 * (kidx / 10);
        float v = Ws[((size_t)l * DH + k) * 640 + q * 64 + f] * 0.1f;
        BtP[tid] = f2bf(v);
    } else if (tid < N_BTP + N_WCB) {
        int r0 = tid - N_BTP;
        int l = r0 / 2048, r = r0 % 2048;
        int tile = r / 1024, rr = r % 1024;
        int ln = rr / 16, idx = rr % 16;
        int t2 = idx / 8, e = idx % 8;
        int k = t2 * 32 + (ln >> 4) * 8 + e;
        int jc = ln & 15;
        int j = tile * 16 + jc;
        float v = 0.f;
        if (j < 20) {
            int hh = j % NHD;
            const float* a = ((j < NHD) ? asrc : adst) + (size_t)l * NHD * DH + hh * DH;
            const float* w = Ws + ((size_t)l * DH + k) * 640 + hh * DH;
            float s = 0.f;
#pragma unroll
            for (int f = 0; f < DH; ++f) s += w[f] * a[f];
            v = s;
        }
        WcB[r0] = f2bf(v);
    } else if (tid < N_BTP + N_WCB + N_EMB) {
        int r0 = tid - N_BTP - N_WCB;
        int c = r0 >> 6, k = r0 & 63;
        float v = (k < DIN) ? Wemb[(size_t)k * DH + c] : 0.f;
        __bf16 hi = (__bf16)v;
        BH[r0] = __builtin_bit_cast(unsigned short, hi);
        BL[r0] = __builtin_bit_cast(unsigned short, (__bf16)(v - (float)hi));
    } else if (tid < N_BTP + N_WCB + N_EMB + N_WET) {
        int t3 = tid - N_BTP - N_WCB - N_EMB;
        int l = t3 / 160, rr = t3 % 160;
        int hh = rr / 16, d = rr % 16;
        const float* a = aedge + (size_t)l * NHD * DH + hh * DH;
        const float* w = We_in + ((size_t)l * DE + d) * 640 + hh * DH;
        float s = 0.f;
#pragma unroll
        for (int f = 0; f < DH; ++f) s += w[f] * a[f];
        WeT[l * 160 + hh * 16 + d] = s;
    } else if (tid < N_PRE) {
        cnt[tid - (N_BTP + N_WCB + N_EMB + N_WET)] = 0;
    }
}

// ---------------- merged: embedding MFMA + layer-0 scores (blocks < EMB_BLOCKS) | a_e dots (rest) ----
constexpr int EMB_BLOCKS = (NN + 63) / 64;                 // 782
constexpr int AE_BLOCKS  = (E2 * NHD + 255) / 256;         // 7813
__global__ __launch_bounds__(256) void k_embae(const float* __restrict__ x,
        const unsigned short* __restrict__ BH, const unsigned short* __restrict__ BL,
        const float* __restrict__ bemb, const unsigned short* __restrict__ WcB,
        __half* __restrict__ hh, float* __restrict__ S,
        const float* __restrict__ ea, const float* __restrict__ loop,
        const float* __restrict__ WeT, const int* __restrict__ eidx,
        __half* __restrict__ aeAll) {
    if (blockIdx.x >= EMB_BLOCKS) {
        // ---- a_e per (slot, head), all 3 layers ----
        int tid = (blockIdx.x - EMB_BLOCKS) * 256 + threadIdx.x;
        if (tid >= E2 * NHD) return;
        int s = tid / NHD, h = tid - (tid / NHD) * NHD;
        int eid = eidx[s];
        const float* ar = (eid < NE) ? (ea + (size_t)eid * DE) : (loop + (size_t)(eid - NE) * DE);
        float4 a0 = *(const float4*)(ar + 0);
        float4 a1 = *(const float4*)(ar + 4);
        float4 a2 = *(const float4*)(ar + 8);
        float4 a3 = *(const float4*)(ar + 12);
#pragma unroll
        for (int l = 0; l < NL; ++l) {
            const float* wt = WeT + l * 160 + h * 16;
            float4 w0 = *(const float4*)(wt + 0);
            float4 w1 = *(const float4*)(wt + 4);
            float4 w2 = *(const float4*)(wt + 8);
            float4 w3 = *(const float4*)(wt + 12);
            float v = a0.x*w0.x + a0.y*w0.y + a0.z*w0.z + a0.w*w0.w
                    + a1.x*w1.x + a1.y*w1.y + a1.z*w1.z + a1.w*w1.w
                    + a2.x*w2.x + a2.y*w2.y + a2.z*w2.z + a2.w*w2.w
                    + a3.x*w3.x + a3.y*w3.y + a3.z*w3.z + a3.w*w3.w;
            aeAll[(size_t)l * E2 * NHD + tid] = (__half)v;
        }
        return;
    }
    // ---- embedding via MFMA (hi/lo split) + fused layer-0 scores ----
    __shared__ __align__(16) unsigned short hlb[4][16 * 72];
    const int tid = threadIdx.x;
    const int w = tid >> 6, lane = tid & 63;
    const int la = lane & 15, lb = lane >> 4;
    const int rowbase = blockIdx.x * 64 + w * 16;
    const int nA = rowbase + la;

    v8bf ah[2], al[2];
#pragma unroll
    for (int ks = 0; ks < 2; ++ks) {
        const int k0 = ks * 32 + lb * 8;
        float xv[8];
        if (nA < NN && k0 < DIN) {
            const float* xp = x + (size_t)nA * DIN + k0;
            float4 v0 = *(const float4*)xp;
            float4 v1 = *(const float4*)(xp + 4);
            xv[0]=v0.x; xv[1]=v0.y; xv[2]=v0.z; xv[3]=v0.w;
            xv[4]=v1.x; xv[5]=v1.y; xv[6]=v1.z; xv[7]=v1.w;
        } else {
#pragma unroll
            for (int e = 0; e < 8; ++e) xv[e] = 0.f;
        }
#pragma unroll
        for (int e = 0; e < 8; ++e) {
            __bf16 hi = (__bf16)xv[e];
            ah[ks][e] = hi;
            al[ks][e] = (__bf16)(xv[e] - (float)hi);
        }
    }
    v4f acc[4];
#pragma unroll
    for (int ct = 0; ct < 4; ++ct) acc[ct] = (v4f){0.f, 0.f, 0.f, 0.f};
#pragma unroll
    for (int ct = 0; ct < 4; ++ct) {
#pragma unroll
        for (int ks = 0; ks < 2; ++ks) {
            const int boff = (ct * 16 + la) * 64 + ks * 32 + lb * 8;
            v8s bh = *(const v8s*)&BH[boff];
            v8s bl = *(const v8s*)&BL[boff];
            acc[ct] = MFB(ah[ks], bh, acc[ct]);
            acc[ct] = MFB(al[ks], bh, acc[ct]);
            acc[ct] = MFB(ah[ks], bl, acc[ct]);
        }
    }
#pragma unroll
    for (int ct = 0; ct < 4; ++ct) {
        const int c = ct * 16 + la;
        const float bi = bemb[c];
#pragma unroll
        for (int r = 0; r < 4; ++r) {
            const int row = lb * 4 + r;
            const int n = rowbase + row;
            float v = acc[ct][r] + bi;
            if (n < NN) hh[(size_t)n * DH + c] = (__half)v;
            hlb[w][row * 72 + c] = f2bf(v);
        }
    }
    __syncthreads();
    v4f s0 = {0.f,0.f,0.f,0.f}, s1 = {0.f,0.f,0.f,0.f};
#pragma unroll
    for (int t = 0; t < 2; ++t) {
        v8s av = *(const v8s*)&hlb[w][la * 72 + t * 32 + lb * 8];
        v8s b0 = *(const v8s*)&WcB[(size_t)(lane) * 16 + t * 8];
        v8s b1 = *(const v8s*)&WcB[(size_t)(64 + lane) * 16 + t * 8];
        s0 = MF(av, b0, s0);
        s1 = MF(av, b1, s1);
    }
#pragma unroll
    for (int r = 0; r < 4; ++r) {
        const int n = rowbase + lb * 4 + r;
        if (n < NN) {
            S[(size_t)n * 20 + la] = s0[r];
            if (la < 4) S[(size_t)n * 20 + 16 + la] = s1[r];
        }
    }
}

// ---------------- fused layer: wave-private softmax (0a/0b) -> pk-f16 agg -> MFMA -> epilogue -> next-S ----
__global__ __launch_bounds__(256) void k_layer(
        const float* __restrict__ Sin, const __half* __restrict__ ae,
        __half* __restrict__ wraw,
        const int* __restrict__ snl12, const int* __restrict__ scsr,
        const __half* __restrict__ hinh,
        const unsigned short* __restrict__ BtP, const unsigned short* __restrict__ WcB,
        int do_s, float* __restrict__ Sout,
        const float* __restrict__ bias, const float* __restrict__ gam,
        const float* __restrict__ bet, const float* __restrict__ mean,
        const float* __restrict__ var, __half* __restrict__ houth) {
    __shared__ __align__(16) unsigned short Gl[16 * 648];   // 20736 B (rows wave-private until Phase B)
    __shared__ __align__(8)  __half wL[16 * 120];           // 3840 B: [li][s*10+h], s<12

    const int tid = threadIdx.x;
    const int w = tid >> 6, lane = tid & 63;
    const int blk = blockIdx.x;
    const int nb4 = blk * 16 + w * 4;
    const unsigned* wrawu = (const unsigned*)wraw;

    // ---- meta: 4 nodes x 16 ints maps exactly onto 64 lanes ----
    const int meta = snl12[nb4 * 16 + lane];

    // ---- Phase 0a shuffles + CRITICAL-PATH loads issued FIRST ----
    const int i0a = (lane < 48) ? (lane / 12) : 0;
    const int s0a = (lane < 48) ? (lane - i0a * 12) : 0;
    const int sn_a  = __shfl(meta, i0a * 16 + s0a);
    const int deg_a = __shfl(meta, i0a * 16 + 12);
    const int r0_a  = __shfl(meta, i0a * 16 + 13);
    const bool act0a = (lane < 48) && (s0a < deg_a);
    float4 t0 = {0,0,0,0}, t1 = {0,0,0,0};
    float2 t2 = {0,0};
    unsigned ew[5] = {0,0,0,0,0};
    if (act0a) {
        const float* sr = Sin + (size_t)sn_a * 20;
        const unsigned* aer = (const unsigned*)ae + (size_t)(r0_a + s0a) * 5;
        t0 = *(const float4*)sr;
        t1 = *(const float4*)(sr + 4);
        t2 = *(const float2*)(sr + 8);
#pragma unroll
        for (int p = 0; p < 5; ++p) ew[p] = aer[p];
    }
    // 0b's sd load issued early too
    const int i0b = (lane < 40) ? (lane / 10) : 0;
    const int h_b = (lane < 40) ? (lane - i0b * 10) : 0;
    const int deg_b = __shfl(meta, i0b * 16 + 12);
    const int r0_b  = __shfl(meta, i0b * 16 + 13);
    float sd = 0.f;
    if (lane < 40) sd = Sin[(size_t)(nb4 + i0b) * 20 + 10 + h_b];

    // ---- off-critical-path hv gathers (latency overlaps Phase 0) ----
    __half hv[4][6];
    __half hv2[4][6];
#pragma unroll
    for (int i = 0; i < 4; ++i) {
#pragma unroll
        for (int j = 0; j < 6; ++j) {
            int sv = RLI(meta, i * 16 + j);
            hv[i][j] = hinh[(size_t)sv * DH + lane];
        }
        const int deg_i = RLI(meta, i * 16 + 12);   // wave-uniform
        if (deg_i > 6) {
#pragma unroll
            for (int j = 0; j < 6; ++j) {
                int sv = RLI(meta, i * 16 + 6 + j);
                hv2[i][j] = hinh[(size_t)sv * DH + lane];
            }
        }
    }

    // ---- Phase 0a: per-(node,slot) partial alpha = S_src + ae (wave-private) ----
    if (act0a) {
        const int li = w * 4 + i0a;
        float as_[10] = {t0.x,t0.y,t0.z,t0.w,t1.x,t1.y,t1.z,t1.w,t2.x,t2.y};
        float* aSrow = (float*)&Gl[li * 648];
#pragma unroll
        for (int p = 0; p < 5; ++p) {
            __half2 eh = __builtin_bit_cast(__half2, ew[p]);
            float2 fp = {as_[2*p] + __low2float(eh), as_[2*p+1] + __high2float(eh)};
            *(float2*)&aSrow[s0a * 10 + 2 * p] = fp;
        }
    }
    __builtin_amdgcn_wave_barrier();

    // ---- Phase 0b: per-(node,head) softmax over aS (lanes<40, wave-private) ----
    if (lane < 40) {
        const int i0 = i0b, h = h_b;
        const int li = w * 4 + i0;
        const int n = nb4 + i0;
        const int deg = deg_b, r0 = r0_b;
        const float* aSrow = (const float*)&Gl[li * 648];
        float aL[12];
        float m = -1e30f;
#pragma unroll
        for (int s = 0; s < 12; ++s) {
            float a = -1e30f;
            if (s < deg) {
                a = aSrow[s * 10 + h] + sd;
                a = (a > 0.f) ? a : 0.2f * a;
                m = fmaxf(m, a);
            }
            aL[s] = a;
        }
        if (deg > 12) {                       // extremely rare
            for (int s = 12; s < deg; ++s) {
                int sn = scsr[r0 + s];
                float a = Sin[(size_t)sn * 20 + h] + sd + (float)ae[(size_t)(r0 + s) * NHD + h];
                a = (a > 0.f) ? a : 0.2f * a;
                wraw[(size_t)(r0 + s) * NHD + h] = (__half)a;
                m = fmaxf(m, a);
            }
        }
        float z = 0.f;
#pragma unroll
        for (int s = 0; s < 12; ++s) {
            float e = (s < deg) ? __expf(aL[s] - m) : 0.f;
            aL[s] = e;
            z += e;
        }
        for (int s = 12; s < deg; ++s) {
            float e = __expf((float)wraw[(size_t)(r0 + s) * NHD + h] - m);
            wraw[(size_t)(r0 + s) * NHD + h] = (__half)e;
            z += e;
        }
        float zi = 1.f / z;
#pragma unroll
        for (int s = 0; s < 12; ++s)
            wL[li * 120 + s * 10 + h] = (__half)(aL[s] * zi);
        for (int s = 12; s < deg; ++s)
            wraw[(size_t)(r0 + s) * NHD + h] =
                (__half)((float)wraw[(size_t)(r0 + s) * NHD + h] * zi);
    }
    __builtin_amdgcn_wave_barrier();

    // ---- Phase A: readlane broadcasts -> packed-f16 FMA ----
    const unsigned* wLu = (const unsigned*)wL;
    int wfu[4];
#pragma unroll
    for (int i = 0; i < 4; ++i)
        wfu[i] = (int)wLu[(w * 4 + i) * 60 + (lane & 31)];
#pragma unroll
    for (int i = 0; i < 4; ++i) {
        const int li = w * 4 + i;
        const int deg = RLI(meta, i * 16 + 12);
        const int r0  = RLI(meta, i * 16 + 13);
        __half2 g[5];
#pragma unroll
        for (int p = 0; p < 5; ++p) g[p] = __half2{(__half)0.f, (__half)0.f};
#pragma unroll
        for (int j = 0; j < 6; ++j) {
            __half2 hvd = __half2half2(hv[i][j]);
#pragma unroll
            for (int p = 0; p < 5; ++p)
                g[p] = __hfma2(RLH2(wfu[i], j * 5 + p), hvd, g[p]);
        }
        if (deg > 6) {
            // chunk 1: slots 6..11 — weights from LDS, hv2 prefetched upfront
            {
                int w2 = (lane < 30) ? (int)wLu[li * 60 + 30 + lane] : 0;
#pragma unroll
                for (int j = 0; j < 6; ++j) {
                    __half2 hvd = __half2half2(hv2[i][j]);
#pragma unroll
                    for (int p = 0; p < 5; ++p)
                        g[p] = __hfma2(RLH2(w2, j * 5 + p), hvd, g[p]);
                }
            }
            // chunks >= 12: very rare, via scsr + wraw
            for (int c0 = 12; c0 < deg; c0 += 6) {
                const int rem = deg - c0;
                int w2 = (lane < 30 && (lane / 5) < rem)
                         ? (int)wrawu[(size_t)(r0 + c0) * 5 + lane] : 0;
                int s2 = (lane < 6 && c0 + lane < deg) ? scsr[r0 + c0 + lane] : 0;
                __half hv3[6];
#pragma unroll
                for (int j = 0; j < 6; ++j) {
                    int sv = RLI(s2, j);
                    hv3[j] = hinh[(size_t)sv * DH + lane];
                }
#pragma unroll
                for (int j = 0; j < 6; ++j) {
                    __half2 hvd = __half2half2(hv3[j]);
#pragma unroll
                    for (int p = 0; p < 5; ++p)
                        g[p] = __hfma2(RLH2(w2, j * 5 + p), hvd, g[p]);
                }
            }
        }
        // write G row: G[li][k*10+q], lane=k -> 5 packed dwords
        const int base = li * 648 + lane * 10;
#pragma unroll
        for (int p = 0; p < 5; ++p) {
            float f0 = __low2float(g[p]), f1 = __high2float(g[p]);
            unsigned u = (unsigned)f2bf(f0) | ((unsigned)f2bf(f1) << 16);
            *(unsigned*)&Gl[base + 2 * p] = u;
        }
    }
    __syncthreads();

    // ---- Phase B: xc = G @ B, one 16x16 col-tile per wave, K=640; BtP coalesced ----
    const int la = lane & 15, lb = lane >> 4;
    v4f acc = {0.f, 0.f, 0.f, 0.f};
    const unsigned short* bp = BtP + (size_t)w * 20 * 512;
#pragma unroll 5
    for (int t = 0; t < 20; ++t) {
        v8s av = *(const v8s*)&Gl[la * 648 + t * 32 + lb * 8];
        v8s bv = *(const v8s*)&bp[t * 512 + lane * 8];
        acc = MF(av, bv, acc);
    }
    __syncthreads();      // Gl reads done; epilogue reuses Gl as bf16 h-tile

    // ---- epilogue: bias + BN + gelu + residual (f16 h); stash hout tile (bf16) in LDS ----
    unsigned short* hlb = Gl;           // [16][72] bf16 (alias)
    const int f = w * 16 + la;
    const float bi = bias[f], gm = gam[f], bt_ = bet[f], mu = mean[f];
    const float iv = rsqrtf(var[f] + 1e-5f);
#pragma unroll
    for (int r = 0; r < 4; ++r) {
        const int local = lb * 4 + r;
        const int n = blk * 16 + local;
        float hvold = (float)hinh[(size_t)n * DH + f];
        float v = acc[r] + bi;
        v = (v - mu) * gm * iv + bt_;
        v = 0.5f * v * (1.0f + erff(v * 0.70710678118654752f));
        float hnew = hvold + v;
        houth[(size_t)n * DH + f] = (__half)hnew;
        hlb[local * 72 + f] = f2bf(hnew);
    }

    // ---- fused next-layer scores: S[16][20] via MFMA on 2 waves ----
    if (do_s) {
        __syncthreads();
        if (w < 2) {
            v4f sa = {0.f, 0.f, 0.f, 0.f};
#pragma unroll
            for (int t = 0; t < 2; ++t) {
                v8s av = *(const v8s*)&hlb[la * 72 + t * 32 + lb * 8];
                v8s bv = *(const v8s*)&WcB[(size_t)(w * 64 + lane) * 16 + t * 8];
                sa = MF(av, bv, sa);
            }
#pragma unroll
            for (int r = 0; r < 4; ++r) {
                const int n = blk * 16 + lb * 4 + r;
                if (w == 0) Sout[(size_t)n * 20 + la] = sa[r];
                else if (la < 4) Sout[(size_t)n * 20 + 16 + la] = sa[r];
            }
        }
    }
}

// ---------------- readout: out[g] = (segsum(hh)[g] @ W_out + cnt*b_out) / max(cnt,1) ----------------
__global__ __launch_bounds__(256) void k_gout(const __half* __restrict__ hh,
        const float* __restrict__ W, const float* __restrict__ b,
        const int* __restrict__ grp, float* __restrict__ out) {
    __shared__ float Wl[DH * DOUTC];  // 32 KB
    __shared__ float hl[4][DH];
    __shared__ float cl[4];
    for (int i = threadIdx.x; i < DH * DOUTC; i += 256) Wl[i] = W[i];
    int w = threadIdx.x >> 6, lane = threadIdx.x & 63;
    int g = blockIdx.x * 4 + w;
    int r0 = grp[g], r1 = grp[g + 1];
    float s = 0.f;
    for (int n = r0; n < r1; ++n) s += (float)hh[(size_t)n * DH + lane];
    hl[w][lane] = s;
    if (lane == 0) cl[w] = (float)(r1 - r0);
    __syncthreads();
    for (int idx = threadIdx.x; idx < 4 * DOUTC; idx += 256) {
        int gi = idx >> 7, c = idx & 127;
        float cnt = cl[gi];
        float inv = 1.f / fmaxf(cnt, 1.f);
        float acc = cnt * b[c];
        const float* hr = hl[gi];
#pragma unroll 16
        for (int k = 0; k < DH; ++k) acc += hr[k] * Wl[k * DOUTC + c];
        out[(size_t)(blockIdx.x * 4 + gi) * DOUTC + c] = acc * inv;
    }
}

// ---------------- launcher ----------------
extern "C" void kernel_launch(void* const* d_in, const int* in_sizes, int n_in,
                              void* d_out, int out_size, void* d_ws, size_t ws_size,
                              hipStream_t stream) {
    const float* x        = (const float*)d_in[0];
    const float* edge_attr= (const float*)d_in[1];
    const float* W_emb    = (const float*)d_in[2];
    const float* b_emb    = (const float*)d_in[3];
    const float* Ws       = (const float*)d_in[4];
    const float* att_src  = (const float*)d_in[5];
    const float* att_dst  = (const float*)d_in[6];
    const float* att_edge = (const float*)d_in[7];
    const float* W_edge   = (const float*)d_in[8];
    const float* bias     = (const float*)d_in[9];
    const float* bn_gamma = (const float*)d_in[10];
    const float* bn_beta  = (const float*)d_in[11];
    const float* bn_mean  = (const float*)d_in[12];
    const float* bn_var   = (const float*)d_in[13];
    const float* W_out    = (const float*)d_in[14];
    const float* b_out    = (const float*)d_in[15];
    const int*   srcp     = (const int*)d_in[16];
    const int*   dstp     = srcp + NE;
    const int*   batch    = (const int*)d_in[17];
    float* out = (float*)d_out;

    char* wsb = (char*)d_ws;
    size_t off = 0;
    auto alloc = [&](size_t bytes) -> void* {
        void* p = (void*)(wsb + off);
        off += (bytes + 255) & ~(size_t)255;
        return p;
    };
    __half* hh0   = (__half*)alloc((size_t)NN * DH * 2);
    __half* hh1   = (__half*)alloc((size_t)NN * DH * 2);
    float*  S0    = (float*)alloc((size_t)NN * 20 * 4);
    float*  S1    = (float*)alloc((size_t)NN * 20 * 4);
    __half* wraw  = (__half*)alloc((size_t)E2 * NHD * 2);
    __half* aeAll = (__half*)alloc((size_t)NL * E2 * NHD * 2);
    float*  loop  = (float*)alloc((size_t)NN * DE * 4);
    int*    cnt   = (int*)alloc((size_t)NN * 4);
    int*    rp    = (int*)alloc((size_t)(NN + 1) * 4);
    int*    cursor= (int*)alloc((size_t)NN * 4);
    int*    eidx  = (int*)alloc((size_t)E2 * 4);
    int*    scsr  = (int*)alloc((size_t)E2 * 4);
    int*    snl12 = (int*)alloc((size_t)NN * 16 * 4);
    int*    grp   = (int*)alloc((size_t)(NG + 1) * 4);
    float*  WeT   = (float*)alloc((size_t)NL * 160 * 4);
    unsigned short* BtP = (unsigned short*)alloc((size_t)NL * 40960 * 2);
    unsigned short* WcB = (unsigned short*)alloc((size_t)NL * 2048 * 2);
    unsigned short* BH  = (unsigned short*)alloc((size_t)DH * 64 * 2);
    unsigned short* BL  = (unsigned short*)alloc((size_t)DH * 64 * 2);

    // constants + cnt zero (no CSR deps) first
    k_prep<<<(N_PRE + 255) / 256, 256, 0, stream>>>(
        Ws, att_src, att_dst, W_edge, att_edge, W_emb, BtP, WcB, BH, BL, WeT, cnt);

    // preprocessing: CSR + merged metadata/self-loop/graph-ptr pass
    k_cnt<<<(NE + 255) / 256, 256, 0, stream>>>(dstp, cnt);
    k_scan<<<SCAN_NB, SCAN_B, 0, stream>>>(cnt, rp, cursor);
    k_csr_fill<<<(E2 + 255) / 256, 256, 0, stream>>>(srcp, dstp, rp, cursor, eidx, scsr);
    k_misc<<<(NN * 18 + 255) / 256, 256, 0, stream>>>(rp, scsr, eidx, cnt, edge_attr,
                                                      batch, snl12, grp, loop);

    // merged: embedding MFMA + layer-0 scores | a_e dots for all layers
    k_embae<<<EMB_BLOCKS + AE_BLOCKS, 256, 0, stream>>>(
        x, BH, BL, b_emb, WcB, hh0, S0, edge_attr, loop, WeT, eidx, aeAll);

    __half* hhb[2] = {hh0, hh1};
    float*  Sb[2]  = {S0, S1};
    for (int l = 0; l < NL; ++l) {
        __half* hinh  = hhb[l & 1];
        __half* houth = hhb[(l + 1) & 1];
        float*  Sin   = Sb[l & 1];
        float*  Sout  = Sb[(l + 1) & 1];
        k_layer<<<NN / 16, 256, 0, stream>>>(
            Sin, aeAll + (size_t)l * E2 * NHD, wraw, snl12, scsr, hinh,
            BtP + (size_t)l * 40960,
            WcB + (size_t)(l + 1 < NL ? l + 1 : 0) * 2048,
            (l + 1 < NL) ? 1 : 0, Sout,
            bias + l * DH, bn_gamma + l * DH, bn_beta + l * DH,
            bn_mean + l * DH, bn_var + l * DH, houth);
    }
    __half* hfinh = hhb[NL & 1];

    // readout (f16 h shadow)
    k_gout<<<NG / 4, 256, 0, stream>>>(hfinh, W_out, b_out, grp, out);
}

// Round 21
// 183.891 us; speedup vs baseline: 1.1081x; 1.1081x over previous
//
#include <hip/hip_runtime.h>
#include <hip/hip_fp16.h>
#include <math.h>

// ---------------- problem constants ----------------
constexpr int NN   = 50000;          // nodes
constexpr int NE   = 150000;         // edges
constexpr int DIN  = 48;
constexpr int DH   = 64;
constexpr int DE   = 16;
constexpr int NHD  = 10;             // heads
constexpr int NL   = 3;              // layers
constexpr int DOUTC= 128;
constexpr int NG   = 4096;           // graphs
constexpr int E2   = NE + NN;        // edges incl self loops (200000)
constexpr int SCAN_B  = 256;
constexpr int SCAN_NB = (NN + SCAN_B - 1) / SCAN_B;   // 196

typedef __bf16 v8bf __attribute__((ext_vector_type(8)));
typedef short  v8s  __attribute__((ext_vector_type(8)));
typedef float  v4f  __attribute__((ext_vector_type(4)));

__device__ inline unsigned short f2bf(float f) {
    unsigned u = __builtin_bit_cast(unsigned, f);
    unsigned r = (u + 0x7FFFu + ((u >> 16) & 1u)) >> 16;
    return (unsigned short)r;
}

__device__ inline v4f MF(v8s a, v8s b, v4f c) {
    return __builtin_amdgcn_mfma_f32_16x16x32_bf16(
        __builtin_bit_cast(v8bf, a), __builtin_bit_cast(v8bf, b), c, 0, 0, 0);
}
__device__ inline v4f MFB(v8bf a, v8s b, v4f c) {
    return __builtin_amdgcn_mfma_f32_16x16x32_bf16(
        a, __builtin_bit_cast(v8bf, b), c, 0, 0, 0);
}

// broadcast from a compile-time lane (no LDS)
#define RLI(v, l) __builtin_amdgcn_readlane((v), (l))
#define RLH2(v, l) __builtin_bit_cast(__half2, __builtin_amdgcn_readlane(__builtin_bit_cast(int, (v)), (l)))

// ---------------- preprocessing ----------------
__global__ void k_cnt(const int* __restrict__ dst, int* __restrict__ cnt) {
    int e = blockIdx.x * blockDim.x + threadIdx.x;
    if (e < NE) atomicAdd(&cnt[dst[e]], 1);
}

__global__ void k_scan_a(const int* __restrict__ cnt, int* __restrict__ bsum) {
    __shared__ int s[SCAN_B];
    int i = blockIdx.x * SCAN_B + threadIdx.x;
    s[threadIdx.x] = (i < NN) ? (cnt[i] + 1) : 0;   // +1 = self loop
    __syncthreads();
    for (int off = SCAN_B / 2; off > 0; off >>= 1) {
        if (threadIdx.x < off) s[threadIdx.x] += s[threadIdx.x + off];
        __syncthreads();
    }
    if (threadIdx.x == 0) bsum[blockIdx.x] = s[0];
}

// block offset computed in-kernel; also zeroes cursor
__global__ void k_scan_c(const int* __restrict__ cnt, const int* __restrict__ bsum,
                         int* __restrict__ rp, int* __restrict__ cursor) {
    __shared__ int s[SCAN_B];
    __shared__ int boff_s;
    const int t = threadIdx.x;
    int partial = (t < SCAN_NB && t < blockIdx.x) ? bsum[t] : 0;
    s[t] = partial;
    __syncthreads();
    for (int off = SCAN_B / 2; off > 0; off >>= 1) {
        if (t < off) s[t] += s[t + off];
        __syncthreads();
    }
    if (t == 0) boff_s = s[0];
    __syncthreads();
    const int boff = boff_s;
    __syncthreads();
    int i = blockIdx.x * SCAN_B + t;
    if (i < NN) cursor[i] = 0;
    int v = (i < NN) ? (cnt[i] + 1) : 0;
    s[t] = v;
    __syncthreads();
    for (int off = 1; off < SCAN_B; off <<= 1) {
        int tv = (t >= off) ? s[t - off] : 0;
        __syncthreads();
        s[t] += tv;
        __syncthreads();
    }
    if (i < NN) {
        int excl = boff + s[t] - v;
        rp[i] = excl;
        if (i == NN - 1) rp[NN] = excl + v;
    }
}

__global__ void k_csr_fill(const int* __restrict__ src, const int* __restrict__ dst,
                           const int* __restrict__ rp, int* __restrict__ cursor,
                           int* __restrict__ eidx, int* __restrict__ scsr) {
    int e = blockIdx.x * blockDim.x + threadIdx.x;
    if (e >= E2) return;
    int d  = (e < NE) ? dst[e] : (e - NE);
    int sn = (e < NE) ? src[e] : d;
    int pos = atomicAdd(&cursor[d], 1);
    int s = rp[d] + pos;
    eidx[s] = e; scsr[s] = sn;
}

// merged: snl12 metadata + graph row ptrs + self-loop attrs (per-node, vectorized)
__global__ void k_misc(const int* __restrict__ rp, const int* __restrict__ scsr,
                       const int* __restrict__ eidx, const int* __restrict__ cnt,
                       const float* __restrict__ ea, const int* __restrict__ batch,
                       int* __restrict__ snl12, int* __restrict__ grp,
                       float* __restrict__ loop) {
    int tid = blockIdx.x * blockDim.x + threadIdx.x;
    if (tid < NN * 16) {
        int n = tid >> 4, j = tid & 15;
        int r0 = rp[n], deg = rp[n + 1] - r0;
        int v;
        if (j < 12)      v = (j < deg) ? scsr[r0 + j] : 0;
        else if (j == 12) v = deg;
        else if (j == 13) v = r0;
        else             v = 0;
        snl12[tid] = v;
    } else if (tid < NN * 17) {
        int n = tid - NN * 16;
        int b = batch[n];
        int pb = (n == 0) ? -1 : batch[n - 1];
        for (int g = pb + 1; g <= b; ++g) grp[g] = n;
        if (n == NN - 1) for (int g = b + 1; g <= NG; ++g) grp[g] = NN;
    } else if (tid < NN * 18) {
        int n = tid - NN * 17;
        int r0 = rp[n], r1 = rp[n + 1];
        float4 a0 = {0.f,0.f,0.f,0.f}, a1 = {0.f,0.f,0.f,0.f};
        float4 a2 = {0.f,0.f,0.f,0.f}, a3 = {0.f,0.f,0.f,0.f};
        for (int q = r0; q < r1; ++q) {
            int eid = eidx[q];
            if (eid < NE) {
                const float* ar = ea + (size_t)eid * DE;
                float4 b0 = *(const float4*)(ar + 0);
                float4 b1 = *(const float4*)(ar + 4);
                float4 b2 = *(const float4*)(ar + 8);
                float4 b3 = *(const float4*)(ar + 12);
                a0.x+=b0.x; a0.y+=b0.y; a0.z+=b0.z; a0.w+=b0.w;
                a1.x+=b1.x; a1.y+=b1.y; a1.z+=b1.z; a1.w+=b1.w;
                a2.x+=b2.x; a2.y+=b2.y; a2.z+=b2.z; a2.w+=b2.w;
                a3.x+=b3.x; a3.y+=b3.y; a3.z+=b3.z; a3.w+=b3.w;
            }
        }
        int c = cnt[n];
        float inv = (c > 1) ? (1.0f / (float)c) : 1.0f;
        a0.x*=inv; a0.y*=inv; a0.z*=inv; a0.w*=inv;
        a1.x*=inv; a1.y*=inv; a1.z*=inv; a1.w*=inv;
        a2.x*=inv; a2.y*=inv; a2.z*=inv; a2.w*=inv;
        a3.x*=inv; a3.y*=inv; a3.z*=inv; a3.w*=inv;
        float* lp = loop + (size_t)n * DE;
        *(float4*)(lp + 0)  = a0;
        *(float4*)(lp + 4)  = a1;
        *(float4*)(lp + 8)  = a2;
        *(float4*)(lp + 12) = a3;
    }
}

// ---------------- merged constant prep: BtP + WcB(direct dot) + W_emb hi/lo + WeT + cnt zero ----------------
constexpr int N_BTP = NL * 40960;      // 122880
constexpr int N_WCB = NL * 2048;       // 6144
constexpr int N_EMB = DH * 64;         // 4096
constexpr int N_WET = NL * DE * NHD;   // 480
constexpr int N_PRE = N_BTP + N_WCB + N_EMB + N_WET + NN;
__global__ void k_prep(const float* __restrict__ Ws, const float* __restrict__ asrc,
                       const float* __restrict__ adst, const float* __restrict__ We_in,
                       const float* __restrict__ aedge, const float* __restrict__ Wemb,
                       unsigned short* __restrict__ BtP, unsigned short* __restrict__ WcB,
                       unsigned short* __restrict__ BH, unsigned short* __restrict__ BL,
                       float* __restrict__ WeT, int* __restrict__ cnt) {
    int tid = blockIdx.x * blockDim.x + threadIdx.x;
    if (tid < N_BTP) {
        int e  = tid & 7;
        int ln = (tid >> 3) & 63;
        int t  = (tid >> 9) % 20;
        int ct = (tid / 10240) & 3;
        int l  = tid / 40960;
        int f = ct * 16 + (ln & 15);
        int kidx = t * 32 + (ln >> 4) * 8 + e;
        int k = kidx / 10, q = kidx - 10 * (kidx / 10);
        float v = Ws[((size_t)l * DH + k) * 640 + q * 64 + f] * 0.1f;
        BtP[tid] = f2bf(v);
    } else if (tid < N_BTP + N_WCB) {
        int r0 = tid - N_BTP;
        int l = r0 / 2048, r = r0 % 2048;
        int tile = r / 1024, rr = r % 1024;
        int ln = rr / 16, idx = rr % 16;
        int t2 = idx / 8, e = idx % 8;
        int k = t2 * 32 + (ln >> 4) * 8 + e;
        int jc = ln & 15;
        int j = tile * 16 + jc;
        float v = 0.f;
        if (j < 20) {
            int hh = j % NHD;
            const float* a = ((j < NHD) ? asrc : adst) + (size_t)l * NHD * DH + hh * DH;
            const float* w = Ws + ((size_t)l * DH + k) * 640 + hh * DH;
            float s = 0.f;
#pragma unroll
            for (int f = 0; f < DH; ++f) s += w[f] * a[f];
            v = s;
        }
        WcB[r0] = f2bf(v);
    } else if (tid < N_BTP + N_WCB + N_EMB) {
        int r0 = tid - N_BTP - N_WCB;
        int c = r0 >> 6, k = r0 & 63;
        float v = (k < DIN) ? Wemb[(size_t)k * DH + c] : 0.f;
        __bf16 hi = (__bf16)v;
        BH[r0] = __builtin_bit_cast(unsigned short, hi);
        BL[r0] = __builtin_bit_cast(unsigned short, (__bf16)(v - (float)hi));
    } else if (tid < N_BTP + N_WCB + N_EMB + N_WET) {
        int t3 = tid - N_BTP - N_WCB - N_EMB;
        int l = t3 / 160, rr = t3 % 160;
        int hh = rr / 16, d = rr % 16;
        const float* a = aedge + (size_t)l * NHD * DH + hh * DH;
        const float* w = We_in + ((size_t)l * DE + d) * 640 + hh * DH;
        float s = 0.f;
#pragma unroll
        for (int f = 0; f < DH; ++f) s += w[f] * a[f];
        WeT[l * 160 + hh * 16 + d] = s;
    } else if (tid < N_PRE) {
        cnt[tid - (N_BTP + N_WCB + N_EMB + N_WET)] = 0;
    }
}

// ---------------- merged: embedding MFMA + layer-0 scores (blocks < EMB_BLOCKS) | a_e dots (rest) ----
constexpr int EMB_BLOCKS = (NN + 63) / 64;                 // 782
constexpr int AE_BLOCKS  = (E2 * NHD + 255) / 256;         // 7813
__global__ __launch_bounds__(256) void k_embae(const float* __restrict__ x,
        const unsigned short* __restrict__ BH, const unsigned short* __restrict__ BL,
        const float* __restrict__ bemb, const unsigned short* __restrict__ WcB,
        __half* __restrict__ hh, float* __restrict__ S,
        const float* __restrict__ ea, const float* __restrict__ loop,
        const float* __restrict__ WeT, const int* __restrict__ eidx,
        __half* __restrict__ aeAll) {
    if (blockIdx.x >= EMB_BLOCKS) {
        // ---- a_e per (slot, head), all 3 layers ----
        int tid = (blockIdx.x - EMB_BLOCKS) * 256 + threadIdx.x;
        if (tid >= E2 * NHD) return;
        int s = tid / NHD, h = tid - (tid / NHD) * NHD;
        int eid = eidx[s];
        const float* ar = (eid < NE) ? (ea + (size_t)eid * DE) : (loop + (size_t)(eid - NE) * DE);
        float4 a0 = *(const float4*)(ar + 0);
        float4 a1 = *(const float4*)(ar + 4);
        float4 a2 = *(const float4*)(ar + 8);
        float4 a3 = *(const float4*)(ar + 12);
#pragma unroll
        for (int l = 0; l < NL; ++l) {
            const float* wt = WeT + l * 160 + h * 16;
            float4 w0 = *(const float4*)(wt + 0);
            float4 w1 = *(const float4*)(wt + 4);
            float4 w2 = *(const float4*)(wt + 8);
            float4 w3 = *(const float4*)(wt + 12);
            float v = a0.x*w0.x + a0.y*w0.y + a0.z*w0.z + a0.w*w0.w
                    + a1.x*w1.x + a1.y*w1.y + a1.z*w1.z + a1.w*w1.w
                    + a2.x*w2.x + a2.y*w2.y + a2.z*w2.z + a2.w*w2.w
                    + a3.x*w3.x + a3.y*w3.y + a3.z*w3.z + a3.w*w3.w;
            aeAll[(size_t)l * E2 * NHD + tid] = (__half)v;
        }
        return;
    }
    // ---- embedding via MFMA (hi/lo split) + fused layer-0 scores ----
    __shared__ __align__(16) unsigned short hlb[4][16 * 72];
    const int tid = threadIdx.x;
    const int w = tid >> 6, lane = tid & 63;
    const int la = lane & 15, lb = lane >> 4;
    const int rowbase = blockIdx.x * 64 + w * 16;
    const int nA = rowbase + la;

    v8bf ah[2], al[2];
#pragma unroll
    for (int ks = 0; ks < 2; ++ks) {
        const int k0 = ks * 32 + lb * 8;
        float xv[8];
        if (nA < NN && k0 < DIN) {
            const float* xp = x + (size_t)nA * DIN + k0;
            float4 v0 = *(const float4*)xp;
            float4 v1 = *(const float4*)(xp + 4);
            xv[0]=v0.x; xv[1]=v0.y; xv[2]=v0.z; xv[3]=v0.w;
            xv[4]=v1.x; xv[5]=v1.y; xv[6]=v1.z; xv[7]=v1.w;
        } else {
#pragma unroll
            for (int e = 0; e < 8; ++e) xv[e] = 0.f;
        }
#pragma unroll
        for (int e = 0; e < 8; ++e) {
            __bf16 hi = (__bf16)xv[e];
            ah[ks][e] = hi;
            al[ks][e] = (__bf16)(xv[e] - (float)hi);
        }
    }
    v4f acc[4];
#pragma unroll
    for (int ct = 0; ct < 4; ++ct) acc[ct] = (v4f){0.f, 0.f, 0.f, 0.f};
#pragma unroll
    for (int ct = 0; ct < 4; ++ct) {
#pragma unroll
        for (int ks = 0; ks < 2; ++ks) {
            const int boff = (ct * 16 + la) * 64 + ks * 32 + lb * 8;
            v8s bh = *(const v8s*)&BH[boff];
            v8s bl = *(const v8s*)&BL[boff];
            acc[ct] = MFB(ah[ks], bh, acc[ct]);
            acc[ct] = MFB(al[ks], bh, acc[ct]);
            acc[ct] = MFB(ah[ks], bl, acc[ct]);
        }
    }
#pragma unroll
    for (int ct = 0; ct < 4; ++ct) {
        const int c = ct * 16 + la;
        const float bi = bemb[c];
#pragma unroll
        for (int r = 0; r < 4; ++r) {
            const int row = lb * 4 + r;
            const int n = rowbase + row;
            float v = acc[ct][r] + bi;
            if (n < NN) hh[(size_t)n * DH + c] = (__half)v;
            hlb[w][row * 72 + c] = f2bf(v);
        }
    }
    __syncthreads();
    v4f s0 = {0.f,0.f,0.f,0.f}, s1 = {0.f,0.f,0.f,0.f};
#pragma unroll
    for (int t = 0; t < 2; ++t) {
        v8s av = *(const v8s*)&hlb[w][la * 72 + t * 32 + lb * 8];
        v8s b0 = *(const v8s*)&WcB[(size_t)(lane) * 16 + t * 8];
        v8s b1 = *(const v8s*)&WcB[(size_t)(64 + lane) * 16 + t * 8];
        s0 = MF(av, b0, s0);
        s1 = MF(av, b1, s1);
    }
#pragma unroll
    for (int r = 0; r < 4; ++r) {
        const int n = rowbase + lb * 4 + r;
        if (n < NN) {
            S[(size_t)n * 20 + la] = s0[r];
            if (la < 4) S[(size_t)n * 20 + 16 + la] = s1[r];
        }
    }
}

// ---------------- fused layer: wave-private softmax (0a/0b) -> pk-f16 agg -> MFMA -> epilogue -> next-S ----
__global__ __launch_bounds__(256) void k_layer(
        const float* __restrict__ Sin, const __half* __restrict__ ae,
        __half* __restrict__ wraw,
        const int* __restrict__ snl12, const int* __restrict__ scsr,
        const __half* __restrict__ hinh,
        const unsigned short* __restrict__ BtP, const unsigned short* __restrict__ WcB,
        int do_s, float* __restrict__ Sout,
        const float* __restrict__ bias, const float* __restrict__ gam,
        const float* __restrict__ bet, const float* __restrict__ mean,
        const float* __restrict__ var, __half* __restrict__ houth) {
    __shared__ __align__(16) unsigned short Gl[16 * 648];   // 20736 B (rows wave-private until Phase B)
    __shared__ __align__(8)  __half wL[16 * 120];           // 3840 B: [li][s*10+h], s<12

    const int tid = threadIdx.x;
    const int w = tid >> 6, lane = tid & 63;
    const int blk = blockIdx.x;
    const int nb4 = blk * 16 + w * 4;
    const unsigned* wrawu = (const unsigned*)wraw;

    // ---- meta: 4 nodes x 16 ints maps exactly onto 64 lanes ----
    const int meta = snl12[nb4 * 16 + lane];

    // ---- issue Phase-A gathers early (latency hides under Phase 0); prefetch slots 6-11 too ----
    __half hv[4][6];
    __half hv2[4][6];
#pragma unroll
    for (int i = 0; i < 4; ++i) {
#pragma unroll
        for (int j = 0; j < 6; ++j) {
            int sv = RLI(meta, i * 16 + j);
            hv[i][j] = hinh[(size_t)sv * DH + lane];
        }
        const int deg_i = RLI(meta, i * 16 + 12);   // wave-uniform
        if (deg_i > 6) {
#pragma unroll
            for (int j = 0; j < 6; ++j) {
                int sv = RLI(meta, i * 16 + 6 + j);
                hv2[i][j] = hinh[(size_t)sv * DH + lane];
            }
        }
    }

    // ---- Phase 0a shuffles: ALL lanes active (clamped indices) ----
    const int i0a = (lane < 48) ? (lane / 12) : 0;
    const int s0a = (lane < 48) ? (lane - i0a * 12) : 0;
    const int sn_a  = __shfl(meta, i0a * 16 + s0a);
    const int deg_a = __shfl(meta, i0a * 16 + 12);
    const int r0_a  = __shfl(meta, i0a * 16 + 13);

    // ---- Phase 0a: per-(node,slot) partial alpha = S_src + ae (lanes<48, wave-private) ----
    if (lane < 48 && s0a < deg_a) {
        const int li = w * 4 + i0a;
        const float* sr = Sin + (size_t)sn_a * 20;
        const unsigned* aer = (const unsigned*)ae + (size_t)(r0_a + s0a) * 5;
        float4 t0 = *(const float4*)sr;
        float4 t1 = *(const float4*)(sr + 4);
        float2 t2 = *(const float2*)(sr + 8);
        unsigned ew[5];
#pragma unroll
        for (int p = 0; p < 5; ++p) ew[p] = aer[p];
        float as_[10] = {t0.x,t0.y,t0.z,t0.w,t1.x,t1.y,t1.z,t1.w,t2.x,t2.y};
        float* aSrow = (float*)&Gl[li * 648];
#pragma unroll
        for (int p = 0; p < 5; ++p) {
            __half2 eh = __builtin_bit_cast(__half2, ew[p]);
            float2 fp = {as_[2*p] + __low2float(eh), as_[2*p+1] + __high2float(eh)};
            *(float2*)&aSrow[s0a * 10 + 2 * p] = fp;
        }
    }
    __builtin_amdgcn_wave_barrier();

    // ---- Phase 0b shuffles: ALL lanes active (clamped indices) ----
    const int i0b = (lane < 40) ? (lane / 10) : 0;
    const int h_b = (lane < 40) ? (lane - i0b * 10) : 0;
    const int deg_b = __shfl(meta, i0b * 16 + 12);
    const int r0_b  = __shfl(meta, i0b * 16 + 13);

    // ---- Phase 0b: per-(node,head) softmax over aS (lanes<40, wave-private) ----
    if (lane < 40) {
        const int i0 = i0b, h = h_b;
        const int li = w * 4 + i0;
        const int n = nb4 + i0;
        const int deg = deg_b, r0 = r0_b;
        const float sd = Sin[(size_t)n * 20 + 10 + h];
        const float* aSrow = (const float*)&Gl[li * 648];
        float aL[12];
        float m = -1e30f;
#pragma unroll
        for (int s = 0; s < 12; ++s) {
            float a = -1e30f;
            if (s < deg) {
                a = aSrow[s * 10 + h] + sd;
                a = (a > 0.f) ? a : 0.2f * a;
                m = fmaxf(m, a);
            }
            aL[s] = a;
        }
        if (deg > 12) {                       // extremely rare
            for (int s = 12; s < deg; ++s) {
                int sn = scsr[r0 + s];
                float a = Sin[(size_t)sn * 20 + h] + sd + (float)ae[(size_t)(r0 + s) * NHD + h];
                a = (a > 0.f) ? a : 0.2f * a;
                wraw[(size_t)(r0 + s) * NHD + h] = (__half)a;
                m = fmaxf(m, a);
            }
        }
        float z = 0.f;
#pragma unroll
        for (int s = 0; s < 12; ++s) {
            float e = (s < deg) ? __expf(aL[s] - m) : 0.f;
            aL[s] = e;
            z += e;
        }
        for (int s = 12; s < deg; ++s) {
            float e = __expf((float)wraw[(size_t)(r0 + s) * NHD + h] - m);
            wraw[(size_t)(r0 + s) * NHD + h] = (__half)e;
            z += e;
        }
        float zi = 1.f / z;
#pragma unroll
        for (int s = 0; s < 12; ++s)
            wL[li * 120 + s * 10 + h] = (__half)(aL[s] * zi);
        for (int s = 12; s < deg; ++s)
            wraw[(size_t)(r0 + s) * NHD + h] =
                (__half)((float)wraw[(size_t)(r0 + s) * NHD + h] * zi);
    }
    __builtin_amdgcn_wave_barrier();

    // ---- Phase A: readlane broadcasts -> packed-f16 FMA ----
    const unsigned* wLu = (const unsigned*)wL;
    int wfu[4];
#pragma unroll
    for (int i = 0; i < 4; ++i)
        wfu[i] = (int)wLu[(w * 4 + i) * 60 + (lane & 31)];
#pragma unroll
    for (int i = 0; i < 4; ++i) {
        const int li = w * 4 + i;
        const int deg = RLI(meta, i * 16 + 12);
        const int r0  = RLI(meta, i * 16 + 13);
        __half2 g[5];
#pragma unroll
        for (int p = 0; p < 5; ++p) g[p] = __half2{(__half)0.f, (__half)0.f};
#pragma unroll
        for (int j = 0; j < 6; ++j) {
            __half2 hvd = __half2half2(hv[i][j]);
#pragma unroll
            for (int p = 0; p < 5; ++p)
                g[p] = __hfma2(RLH2(wfu[i], j * 5 + p), hvd, g[p]);
        }
        if (deg > 6) {
            // chunk 1: slots 6..11 — weights from LDS, hv2 prefetched upfront
            {
                int w2 = (lane < 30) ? (int)wLu[li * 60 + 30 + lane] : 0;
#pragma unroll
                for (int j = 0; j < 6; ++j) {
                    __half2 hvd = __half2half2(hv2[i][j]);
#pragma unroll
                    for (int p = 0; p < 5; ++p)
                        g[p] = __hfma2(RLH2(w2, j * 5 + p), hvd, g[p]);
                }
            }
            // chunks >= 12: very rare, via scsr + wraw
            for (int c0 = 12; c0 < deg; c0 += 6) {
                const int rem = deg - c0;
                int w2 = (lane < 30 && (lane / 5) < rem)
                         ? (int)wrawu[(size_t)(r0 + c0) * 5 + lane] : 0;
                int s2 = (lane < 6 && c0 + lane < deg) ? scsr[r0 + c0 + lane] : 0;
                __half hv3[6];
#pragma unroll
                for (int j = 0; j < 6; ++j) {
                    int sv = RLI(s2, j);
                    hv3[j] = hinh[(size_t)sv * DH + lane];
                }
#pragma unroll
                for (int j = 0; j < 6; ++j) {
                    __half2 hvd = __half2half2(hv3[j]);
#pragma unroll
                    for (int p = 0; p < 5; ++p)
                        g[p] = __hfma2(RLH2(w2, j * 5 + p), hvd, g[p]);
                }
            }
        }
        // write G row: G[li][k*10+q], lane=k -> 5 packed dwords
        const int base = li * 648 + lane * 10;
#pragma unroll
        for (int p = 0; p < 5; ++p) {
            float f0 = __low2float(g[p]), f1 = __high2float(g[p]);
            unsigned u = (unsigned)f2bf(f0) | ((unsigned)f2bf(f1) << 16);
            *(unsigned*)&Gl[base + 2 * p] = u;
        }
    }
    __syncthreads();

    // ---- Phase B: xc = G @ B, one 16x16 col-tile per wave, K=640; BtP coalesced ----
    const int la = lane & 15, lb = lane >> 4;
    v4f acc = {0.f, 0.f, 0.f, 0.f};
    const unsigned short* bp = BtP + (size_t)w * 20 * 512;
#pragma unroll 5
    for (int t = 0; t < 20; ++t) {
        v8s av = *(const v8s*)&Gl[la * 648 + t * 32 + lb * 8];
        v8s bv = *(const v8s*)&bp[t * 512 + lane * 8];
        acc = MF(av, bv, acc);
    }
    __syncthreads();      // Gl reads done; epilogue reuses Gl as bf16 h-tile

    // ---- epilogue: bias + BN + gelu + residual (f16 h); stash hout tile (bf16) in LDS ----
    unsigned short* hlb = Gl;           // [16][72] bf16 (alias)
    const int f = w * 16 + la;
    const float bi = bias[f], gm = gam[f], bt_ = bet[f], mu = mean[f];
    const float iv = rsqrtf(var[f] + 1e-5f);
#pragma unroll
    for (int r = 0; r < 4; ++r) {
        const int local = lb * 4 + r;
        const int n = blk * 16 + local;
        float hvold = (float)hinh[(size_t)n * DH + f];
        float v = acc[r] + bi;
        v = (v - mu) * gm * iv + bt_;
        v = 0.5f * v * (1.0f + erff(v * 0.70710678118654752f));
        float hnew = hvold + v;
        houth[(size_t)n * DH + f] = (__half)hnew;
        hlb[local * 72 + f] = f2bf(hnew);
    }

    // ---- fused next-layer scores: S[16][20] via MFMA on 2 waves ----
    if (do_s) {
        __syncthreads();
        if (w < 2) {
            v4f sa = {0.f, 0.f, 0.f, 0.f};
#pragma unroll
            for (int t = 0; t < 2; ++t) {
                v8s av = *(const v8s*)&hlb[la * 72 + t * 32 + lb * 8];
                v8s bv = *(const v8s*)&WcB[(size_t)(w * 64 + lane) * 16 + t * 8];
                sa = MF(av, bv, sa);
            }
#pragma unroll
            for (int r = 0; r < 4; ++r) {
                const int n = blk * 16 + lb * 4 + r;
                if (w == 0) Sout[(size_t)n * 20 + la] = sa[r];
                else if (la < 4) Sout[(size_t)n * 20 + 16 + la] = sa[r];
            }
        }
    }
}

// ---------------- readout: out[g] = (segsum(hh)[g] @ W_out + cnt*b_out) / max(cnt,1) ----------------
__global__ __launch_bounds__(256) void k_gout(const __half* __restrict__ hh,
        const float* __restrict__ W, const float* __restrict__ b,
        const int* __restrict__ grp, float* __restrict__ out) {
    __shared__ float Wl[DH * DOUTC];  // 32 KB
    __shared__ float hl[4][DH];
    __shared__ float cl[4];
    for (int i = threadIdx.x; i < DH * DOUTC; i += 256) Wl[i] = W[i];
    int w = threadIdx.x >> 6, lane = threadIdx.x & 63;
    int g = blockIdx.x * 4 + w;
    int r0 = grp[g], r1 = grp[g + 1];
    float s = 0.f;
    for (int n = r0; n < r1; ++n) s += (float)hh[(size_t)n * DH + lane];
    hl[w][lane] = s;
    if (lane == 0) cl[w] = (float)(r1 - r0);
    __syncthreads();
    for (int idx = threadIdx.x; idx < 4 * DOUTC; idx += 256) {
        int gi = idx >> 7, c = idx & 127;
        float cnt = cl[gi];
        float inv = 1.f / fmaxf(cnt, 1.f);
        float acc = cnt * b[c];
        const float* hr = hl[gi];
#pragma unroll 16
        for (int k = 0; k < DH; ++k) acc += hr[k] * Wl[k * DOUTC + c];
        out[(size_t)(blockIdx.x * 4 + gi) * DOUTC + c] = acc * inv;
    }
}

// ---------------- launcher ----------------
extern "C" void kernel_launch(void* const* d_in, const int* in_sizes, int n_in,
                              void* d_out, int out_size, void* d_ws, size_t ws_size,
                              hipStream_t stream) {
    const float* x        = (const float*)d_in[0];
    const float* edge_attr= (const float*)d_in[1];
    const float* W_emb    = (const float*)d_in[2];
    const float* b_emb    = (const float*)d_in[3];
    const float* Ws       = (const float*)d_in[4];
    const float* att_src  = (const float*)d_in[5];
    const float* att_dst  = (const float*)d_in[6];
    const float* att_edge = (const float*)d_in[7];
    const float* W_edge   = (const float*)d_in[8];
    const float* bias     = (const float*)d_in[9];
    const float* bn_gamma = (const float*)d_in[10];
    const float* bn_beta  = (const float*)d_in[11];
    const float* bn_mean  = (const float*)d_in[12];
    const float* bn_var   = (const float*)d_in[13];
    const float* W_out    = (const float*)d_in[14];
    const float* b_out    = (const float*)d_in[15];
    const int*   srcp     = (const int*)d_in[16];
    const int*   dstp     = srcp + NE;
    const int*   batch    = (const int*)d_in[17];
    float* out = (float*)d_out;

    char* wsb = (char*)d_ws;
    size_t off = 0;
    auto alloc = [&](size_t bytes) -> void* {
        void* p = (void*)(wsb + off);
        off += (bytes + 255) & ~(size_t)255;
        return p;
    };
    __half* hh0   = (__half*)alloc((size_t)NN * DH * 2);
    __half* hh1   = (__half*)alloc((size_t)NN * DH * 2);
    float*  S0    = (float*)alloc((size_t)NN * 20 * 4);
    float*  S1    = (float*)alloc((size_t)NN * 20 * 4);
    __half* wraw  = (__half*)alloc((size_t)E2 * NHD * 2);
    __half* aeAll = (__half*)alloc((size_t)NL * E2 * NHD * 2);
    float*  loop  = (float*)alloc((size_t)NN * DE * 4);
    int*    cnt   = (int*)alloc((size_t)NN * 4);
    int*    rp    = (int*)alloc((size_t)(NN + 1) * 4);
    int*    cursor= (int*)alloc((size_t)NN * 4);
    int*    eidx  = (int*)alloc((size_t)E2 * 4);
    int*    scsr  = (int*)alloc((size_t)E2 * 4);
    int*    snl12 = (int*)alloc((size_t)NN * 16 * 4);
    int*    bsum  = (int*)alloc((size_t)SCAN_NB * 4);
    int*    grp   = (int*)alloc((size_t)(NG + 1) * 4);
    float*  WeT   = (float*)alloc((size_t)NL * 160 * 4);
    unsigned short* BtP = (unsigned short*)alloc((size_t)NL * 40960 * 2);
    unsigned short* WcB = (unsigned short*)alloc((size_t)NL * 2048 * 2);
    unsigned short* BH  = (unsigned short*)alloc((size_t)DH * 64 * 2);
    unsigned short* BL  = (unsigned short*)alloc((size_t)DH * 64 * 2);

    // constants + cnt zero (no CSR deps) first
    k_prep<<<(N_PRE + 255) / 256, 256, 0, stream>>>(
        Ws, att_src, att_dst, W_edge, att_edge, W_emb, BtP, WcB, BH, BL, WeT, cnt);

    // preprocessing: CSR + merged metadata/self-loop/graph-ptr pass
    k_cnt<<<(NE + 255) / 256, 256, 0, stream>>>(dstp, cnt);
    k_scan_a<<<SCAN_NB, SCAN_B, 0, stream>>>(cnt, bsum);
    k_scan_c<<<SCAN_NB, SCAN_B, 0, stream>>>(cnt, bsum, rp, cursor);
    k_csr_fill<<<(E2 + 255) / 256, 256, 0, stream>>>(srcp, dstp, rp, cursor, eidx, scsr);
    k_misc<<<(NN * 18 + 255) / 256, 256, 0, stream>>>(rp, scsr, eidx, cnt, edge_attr,
                                                      batch, snl12, grp, loop);

    // merged: embedding MFMA + layer-0 scores | a_e dots for all layers
    k_embae<<<EMB_BLOCKS + AE_BLOCKS, 256, 0, stream>>>(
        x, BH, BL, b_emb, WcB, hh0, S0, edge_attr, loop, WeT, eidx, aeAll);

    __half* hhb[2] = {hh0, hh1};
    float*  Sb[2]  = {S0, S1};
    for (int l = 0; l < NL; ++l) {
        __half* hinh  = hhb[l & 1];
        __half* houth = hhb[(l + 1) & 1];
        float*  Sin   = Sb[l & 1];
        float*  Sout  = Sb[(l + 1) & 1];
        k_layer<<<NN / 16, 256, 0, stream>>>(
            Sin, aeAll + (size_t)l * E2 * NHD, wraw, snl12, scsr, hinh,
            BtP + (size_t)l * 40960,
            WcB + (size_t)(l + 1 < NL ? l + 1 : 0) * 2048,
            (l + 1 < NL) ? 1 : 0, Sout,
            bias + l * DH, bn_gamma + l * DH, bn_beta + l * DH,
            bn_mean + l * DH, bn_var + l * DH, houth);
    }
    __half* hfinh = hhb[NL & 1];

    // readout (f16 h shadow)
    k_gout<<<NG / 4, 256, 0, stream>>>(hfinh, W_out, b_out, grp, out);
}

// Round 22
// 182.188 us; speedup vs baseline: 1.1185x; 1.0093x over previous
//
#include <hip/hip_runtime.h>
#include <hip/hip_fp16.h>
#include <math.h>

// ---------------- problem constants ----------------
constexpr int NN   = 50000;          // nodes
constexpr int NE   = 150000;         // edges
constexpr int DIN  = 48;
constexpr int DH   = 64;
constexpr int DE   = 16;
constexpr int NHD  = 10;             // heads
constexpr int NL   = 3;              // layers
constexpr int DOUTC= 128;
constexpr int NG   = 4096;           // graphs
constexpr int E2   = NE + NN;        // edges incl self loops (200000)
constexpr int SCAN_B  = 256;
constexpr int SCAN_NB = (NN + SCAN_B - 1) / SCAN_B;   // 196

typedef __bf16 v8bf __attribute__((ext_vector_type(8)));
typedef short  v8s  __attribute__((ext_vector_type(8)));
typedef float  v4f  __attribute__((ext_vector_type(4)));

__device__ inline unsigned short f2bf(float f) {
    unsigned u = __builtin_bit_cast(unsigned, f);
    unsigned r = (u + 0x7FFFu + ((u >> 16) & 1u)) >> 16;
    return (unsigned short)r;
}

__device__ inline v4f MF(v8s a, v8s b, v4f c) {
    return __builtin_amdgcn_mfma_f32_16x16x32_bf16(
        __builtin_bit_cast(v8bf, a), __builtin_bit_cast(v8bf, b), c, 0, 0, 0);
}
__device__ inline v4f MFB(v8bf a, v8s b, v4f c) {
    return __builtin_amdgcn_mfma_f32_16x16x32_bf16(
        a, __builtin_bit_cast(v8bf, b), c, 0, 0, 0);
}

// broadcast from a compile-time lane (no LDS)
#define RLI(v, l) __builtin_amdgcn_readlane((v), (l))
#define RLH2(v, l) __builtin_bit_cast(__half2, __builtin_amdgcn_readlane(__builtin_bit_cast(int, (v)), (l)))

// ---------------- preprocessing ----------------
__global__ void k_cnt(const int* __restrict__ dst, int* __restrict__ cnt) {
    int e = blockIdx.x * blockDim.x + threadIdx.x;
    if (e < NE) atomicAdd(&cnt[dst[e]], 1);
}

__global__ void k_scan_a(const int* __restrict__ cnt, int* __restrict__ bsum) {
    __shared__ int s[SCAN_B];
    int i = blockIdx.x * SCAN_B + threadIdx.x;
    s[threadIdx.x] = (i < NN) ? (cnt[i] + 1) : 0;   // +1 = self loop
    __syncthreads();
    for (int off = SCAN_B / 2; off > 0; off >>= 1) {
        if (threadIdx.x < off) s[threadIdx.x] += s[threadIdx.x + off];
        __syncthreads();
    }
    if (threadIdx.x == 0) bsum[blockIdx.x] = s[0];
}

// block offset computed in-kernel; also zeroes cursor
__global__ void k_scan_c(const int* __restrict__ cnt, const int* __restrict__ bsum,
                         int* __restrict__ rp, int* __restrict__ cursor) {
    __shared__ int s[SCAN_B];
    __shared__ int boff_s;
    const int t = threadIdx.x;
    int partial = (t < SCAN_NB && t < blockIdx.x) ? bsum[t] : 0;
    s[t] = partial;
    __syncthreads();
    for (int off = SCAN_B / 2; off > 0; off >>= 1) {
        if (t < off) s[t] += s[t + off];
        __syncthreads();
    }
    if (t == 0) boff_s = s[0];
    __syncthreads();
    const int boff = boff_s;
    __syncthreads();
    int i = blockIdx.x * SCAN_B + t;
    if (i < NN) cursor[i] = 0;
    int v = (i < NN) ? (cnt[i] + 1) : 0;
    s[t] = v;
    __syncthreads();
    for (int off = 1; off < SCAN_B; off <<= 1) {
        int tv = (t >= off) ? s[t - off] : 0;
        __syncthreads();
        s[t] += tv;
        __syncthreads();
    }
    if (i < NN) {
        int excl = boff + s[t] - v;
        rp[i] = excl;
        if (i == NN - 1) rp[NN] = excl + v;
    }
}

__global__ void k_csr_fill(const int* __restrict__ src, const int* __restrict__ dst,
                           const int* __restrict__ rp, int* __restrict__ cursor,
                           int* __restrict__ eidx, int* __restrict__ scsr) {
    int e = blockIdx.x * blockDim.x + threadIdx.x;
    if (e >= E2) return;
    int d  = (e < NE) ? dst[e] : (e - NE);
    int sn = (e < NE) ? src[e] : d;
    int pos = atomicAdd(&cursor[d], 1);
    int s = rp[d] + pos;
    eidx[s] = e; scsr[s] = sn;
}

// merged: snl12 metadata + graph row ptrs + self-loop attrs (per-node, vectorized)
__global__ void k_misc(const int* __restrict__ rp, const int* __restrict__ scsr,
                       const int* __restrict__ eidx, const int* __restrict__ cnt,
                       const float* __restrict__ ea, const int* __restrict__ batch,
                       int* __restrict__ snl12, int* __restrict__ grp,
                       float* __restrict__ loop) {
    int tid = blockIdx.x * blockDim.x + threadIdx.x;
    if (tid < NN * 16) {
        int n = tid >> 4, j = tid & 15;
        int r0 = rp[n], deg = rp[n + 1] - r0;
        int v;
        if (j < 12)      v = (j < deg) ? scsr[r0 + j] : 0;
        else if (j == 12) v = deg;
        else if (j == 13) v = r0;
        else             v = 0;
        snl12[tid] = v;
    } else if (tid < NN * 17) {
        int n = tid - NN * 16;
        int b = batch[n];
        int pb = (n == 0) ? -1 : batch[n - 1];
        for (int g = pb + 1; g <= b; ++g) grp[g] = n;
        if (n == NN - 1) for (int g = b + 1; g <= NG; ++g) grp[g] = NN;
    } else if (tid < NN * 18) {
        int n = tid - NN * 17;
        int r0 = rp[n], r1 = rp[n + 1];
        float4 a0 = {0.f,0.f,0.f,0.f}, a1 = {0.f,0.f,0.f,0.f};
        float4 a2 = {0.f,0.f,0.f,0.f}, a3 = {0.f,0.f,0.f,0.f};
        for (int q = r0; q < r1; ++q) {
            int eid = eidx[q];
            if (eid < NE) {
                const float* ar = ea + (size_t)eid * DE;
                float4 b0 = *(const float4*)(ar + 0);
                float4 b1 = *(const float4*)(ar + 4);
                float4 b2 = *(const float4*)(ar + 8);
                float4 b3 = *(const float4*)(ar + 12);
                a0.x+=b0.x; a0.y+=b0.y; a0.z+=b0.z; a0.w+=b0.w;
                a1.x+=b1.x; a1.y+=b1.y; a1.z+=b1.z; a1.w+=b1.w;
                a2.x+=b2.x; a2.y+=b2.y; a2.z+=b2.z; a2.w+=b2.w;
                a3.x+=b3.x; a3.y+=b3.y; a3.z+=b3.z; a3.w+=b3.w;
            }
        }
        int c = cnt[n];
        float inv = (c > 1) ? (1.0f / (float)c) : 1.0f;
        a0.x*=inv; a0.y*=inv; a0.z*=inv; a0.w*=inv;
        a1.x*=inv; a1.y*=inv; a1.z*=inv; a1.w*=inv;
        a2.x*=inv; a2.y*=inv; a2.z*=inv; a2.w*=inv;
        a3.x*=inv; a3.y*=inv; a3.z*=inv; a3.w*=inv;
        float* lp = loop + (size_t)n * DE;
        *(float4*)(lp + 0)  = a0;
        *(float4*)(lp + 4)  = a1;
        *(float4*)(lp + 8)  = a2;
        *(float4*)(lp + 12) = a3;
    }
}

// ---------------- merged constant prep: BtP + WcB(direct dot) + W_emb hi/lo + WeT + cnt zero ----------------
constexpr int N_BTP = NL * 40960;      // 122880
constexpr int N_WCB = NL * 2048;       // 6144
constexpr int N_EMB = DH * 64;         // 4096
constexpr int N_WET = NL * DE * NHD;   // 480
constexpr int N_PRE = N_BTP + N_WCB + N_EMB + N_WET + NN;
__global__ void k_prep(const float* __restrict__ Ws, const float* __restrict__ asrc,
                       const float* __restrict__ adst, const float* __restrict__ We_in,
                       const float* __restrict__ aedge, const float* __restrict__ Wemb,
                       unsigned short* __restrict__ BtP, unsigned short* __restrict__ WcB,
                       unsigned short* __restrict__ BH, unsigned short* __restrict__ BL,
                       float* __restrict__ WeT, int* __restrict__ cnt) {
    int tid = blockIdx.x * blockDim.x + threadIdx.x;
    if (tid < N_BTP) {
        int e  = tid & 7;
        int ln = (tid >> 3) & 63;
        int t  = (tid >> 9) % 20;
        int ct = (tid / 10240) & 3;
        int l  = tid / 40960;
        int f = ct * 16 + (ln & 15);
        int kidx = t * 32 + (ln >> 4) * 8 + e;
        int k = kidx / 10, q = kidx - 10 * (kidx / 10);
        float v = Ws[((size_t)l * DH + k) * 640 + q * 64 + f] * 0.1f;
        BtP[tid] = f2bf(v);
    } else if (tid < N_BTP + N_WCB) {
        int r0 = tid - N_BTP;
        int l = r0 / 2048, r = r0 % 2048;
        int tile = r / 1024, rr = r % 1024;
        int ln = rr / 16, idx = rr % 16;
        int t2 = idx / 8, e = idx % 8;
        int k = t2 * 32 + (ln >> 4) * 8 + e;
        int jc = ln & 15;
        int j = tile * 16 + jc;
        float v = 0.f;
        if (j < 20) {
            int hh = j % NHD;
            const float* a = ((j < NHD) ? asrc : adst) + (size_t)l * NHD * DH + hh * DH;
            const float* w = Ws + ((size_t)l * DH + k) * 640 + hh * DH;
            float s = 0.f;
#pragma unroll
            for (int f = 0; f < DH; ++f) s += w[f] * a[f];
            v = s;
        }
        WcB[r0] = f2bf(v);
    } else if (tid < N_BTP + N_WCB + N_EMB) {
        int r0 = tid - N_BTP - N_WCB;
        int c = r0 >> 6, k = r0 & 63;
        float v = (k < DIN) ? Wemb[(size_t)k * DH + c] : 0.f;
        __bf16 hi = (__bf16)v;
        BH[r0] = __builtin_bit_cast(unsigned short, hi);
        BL[r0] = __builtin_bit_cast(unsigned short, (__bf16)(v - (float)hi));
    } else if (tid < N_BTP + N_WCB + N_EMB + N_WET) {
        int t3 = tid - N_BTP - N_WCB - N_EMB;
        int l = t3 / 160, rr = t3 % 160;
        int hh = rr / 16, d = rr % 16;
        const float* a = aedge + (size_t)l * NHD * DH + hh * DH;
        const float* w = We_in + ((size_t)l * DE + d) * 640 + hh * DH;
        float s = 0.f;
#pragma unroll
        for (int f = 0; f < DH; ++f) s += w[f] * a[f];
        WeT[l * 160 + hh * 16 + d] = s;
    } else if (tid < N_PRE) {
        cnt[tid - (N_BTP + N_WCB + N_EMB + N_WET)] = 0;
    }
}

// ---------------- merged: embedding MFMA + layer-0 scores (blocks < EMB_BLOCKS) | a_e dots (rest) ----
constexpr int EMB_BLOCKS = (NN + 63) / 64;                 // 782
constexpr int AE_BLOCKS  = (E2 * NHD + 255) / 256;         // 7813
__global__ __launch_bounds__(256) void k_embae(const float* __restrict__ x,
        const unsigned short* __restrict__ BH, const unsigned short* __restrict__ BL,
        const float* __restrict__ bemb, const unsigned short* __restrict__ WcB,
        __half* __restrict__ hh, __half* __restrict__ S,
        const float* __restrict__ ea, const float* __restrict__ loop,
        const float* __restrict__ WeT, const int* __restrict__ eidx,
        __half* __restrict__ aeAll) {
    if (blockIdx.x >= EMB_BLOCKS) {
        // ---- a_e per (slot, head), all 3 layers ----
        int tid = (blockIdx.x - EMB_BLOCKS) * 256 + threadIdx.x;
        if (tid >= E2 * NHD) return;
        int s = tid / NHD, h = tid - (tid / NHD) * NHD;
        int eid = eidx[s];
        const float* ar = (eid < NE) ? (ea + (size_t)eid * DE) : (loop + (size_t)(eid - NE) * DE);
        float4 a0 = *(const float4*)(ar + 0);
        float4 a1 = *(const float4*)(ar + 4);
        float4 a2 = *(const float4*)(ar + 8);
        float4 a3 = *(const float4*)(ar + 12);
#pragma unroll
        for (int l = 0; l < NL; ++l) {
            const float* wt = WeT + l * 160 + h * 16;
            float4 w0 = *(const float4*)(wt + 0);
            float4 w1 = *(const float4*)(wt + 4);
            float4 w2 = *(const float4*)(wt + 8);
            float4 w3 = *(const float4*)(wt + 12);
            float v = a0.x*w0.x + a0.y*w0.y + a0.z*w0.z + a0.w*w0.w
                    + a1.x*w1.x + a1.y*w1.y + a1.z*w1.z + a1.w*w1.w
                    + a2.x*w2.x + a2.y*w2.y + a2.z*w2.z + a2.w*w2.w
                    + a3.x*w3.x + a3.y*w3.y + a3.z*w3.z + a3.w*w3.w;
            aeAll[(size_t)l * E2 * NHD + tid] = (__half)v;
        }
        return;
    }
    // ---- embedding via MFMA (hi/lo split) + fused layer-0 scores ----
    __shared__ __align__(16) unsigned short hlb[4][16 * 72];
    const int tid = threadIdx.x;
    const int w = tid >> 6, lane = tid & 63;
    const int la = lane & 15, lb = lane >> 4;
    const int rowbase = blockIdx.x * 64 + w * 16;
    const int nA = rowbase + la;

    v8bf ah[2], al[2];
#pragma unroll
    for (int ks = 0; ks < 2; ++ks) {
        const int k0 = ks * 32 + lb * 8;
        float xv[8];
        if (nA < NN && k0 < DIN) {
            const float* xp = x + (size_t)nA * DIN + k0;
            float4 v0 = *(const float4*)xp;
            float4 v1 = *(const float4*)(xp + 4);
            xv[0]=v0.x; xv[1]=v0.y; xv[2]=v0.z; xv[3]=v0.w;
            xv[4]=v1.x; xv[5]=v1.y; xv[6]=v1.z; xv[7]=v1.w;
        } else {
#pragma unroll
            for (int e = 0; e < 8; ++e) xv[e] = 0.f;
        }
#pragma unroll
        for (int e = 0; e < 8; ++e) {
            __bf16 hi = (__bf16)xv[e];
            ah[ks][e] = hi;
            al[ks][e] = (__bf16)(xv[e] - (float)hi);
        }
    }
    v4f acc[4];
#pragma unroll
    for (int ct = 0; ct < 4; ++ct) acc[ct] = (v4f){0.f, 0.f, 0.f, 0.f};
#pragma unroll
    for (int ct = 0; ct < 4; ++ct) {
#pragma unroll
        for (int ks = 0; ks < 2; ++ks) {
            const int boff = (ct * 16 + la) * 64 + ks * 32 + lb * 8;
            v8s bh = *(const v8s*)&BH[boff];
            v8s bl = *(const v8s*)&BL[boff];
            acc[ct] = MFB(ah[ks], bh, acc[ct]);
            acc[ct] = MFB(al[ks], bh, acc[ct]);
            acc[ct] = MFB(ah[ks], bl, acc[ct]);
        }
    }
#pragma unroll
    for (int ct = 0; ct < 4; ++ct) {
        const int c = ct * 16 + la;
        const float bi = bemb[c];
#pragma unroll
        for (int r = 0; r < 4; ++r) {
            const int row = lb * 4 + r;
            const int n = rowbase + row;
            float v = acc[ct][r] + bi;
            if (n < NN) hh[(size_t)n * DH + c] = (__half)v;
            hlb[w][row * 72 + c] = f2bf(v);
        }
    }
    __syncthreads();
    v4f s0 = {0.f,0.f,0.f,0.f}, s1 = {0.f,0.f,0.f,0.f};
#pragma unroll
    for (int t = 0; t < 2; ++t) {
        v8s av = *(const v8s*)&hlb[w][la * 72 + t * 32 + lb * 8];
        v8s b0 = *(const v8s*)&WcB[(size_t)(lane) * 16 + t * 8];
        v8s b1 = *(const v8s*)&WcB[(size_t)(64 + lane) * 16 + t * 8];
        s0 = MF(av, b0, s0);
        s1 = MF(av, b1, s1);
    }
#pragma unroll
    for (int r = 0; r < 4; ++r) {
        const int n = rowbase + lb * 4 + r;
        if (n < NN) {
            S[(size_t)n * 20 + la] = (__half)s0[r];
            if (la < 4) S[(size_t)n * 20 + 16 + la] = (__half)s1[r];
        }
    }
}

// ---------------- fused layer: wave-private softmax (0a/0b) -> pk-f16 agg -> MFMA -> epilogue -> next-S ----
// S is f16; Phase 0a = packed half add (S_src + ae); 0b adds sd (f32) + leaky + softmax in f32.
__global__ __launch_bounds__(256) void k_layer(
        const __half* __restrict__ Sin, const __half* __restrict__ ae,
        __half* __restrict__ wraw,
        const int* __restrict__ snl12, const int* __restrict__ scsr,
        const __half* __restrict__ hinh,
        const unsigned short* __restrict__ BtP, const unsigned short* __restrict__ WcB,
        int do_s, __half* __restrict__ Sout,
        const float* __restrict__ bias, const float* __restrict__ gam,
        const float* __restrict__ bet, const float* __restrict__ mean,
        const float* __restrict__ var, __half* __restrict__ houth) {
    __shared__ __align__(16) unsigned short Gl[16 * 648];   // 20736 B (rows wave-private until Phase B)
    __shared__ __align__(8)  __half wL[16 * 120];           // 3840 B: [li][s*10+h], s<12

    const int tid = threadIdx.x;
    const int w = tid >> 6, lane = tid & 63;
    const int blk = blockIdx.x;
    const int nb4 = blk * 16 + w * 4;
    const unsigned* wrawu = (const unsigned*)wraw;

    // ---- meta: 4 nodes x 16 ints maps exactly onto 64 lanes ----
    const int meta = snl12[nb4 * 16 + lane];

    // ---- issue Phase-A gathers early (latency hides under Phase 0); prefetch slots 6-11 too ----
    __half hv[4][6];
    __half hv2[4][6];
#pragma unroll
    for (int i = 0; i < 4; ++i) {
#pragma unroll
        for (int j = 0; j < 6; ++j) {
            int sv = RLI(meta, i * 16 + j);
            hv[i][j] = hinh[(size_t)sv * DH + lane];
        }
        const int deg_i = RLI(meta, i * 16 + 12);   // wave-uniform
        if (deg_i > 6) {
#pragma unroll
            for (int j = 0; j < 6; ++j) {
                int sv = RLI(meta, i * 16 + 6 + j);
                hv2[i][j] = hinh[(size_t)sv * DH + lane];
            }
        }
    }

    // ---- Phase 0a shuffles: ALL lanes active (clamped indices) ----
    const int i0a = (lane < 48) ? (lane / 12) : 0;
    const int s0a = (lane < 48) ? (lane - i0a * 12) : 0;
    const int sn_a  = __shfl(meta, i0a * 16 + s0a);
    const int deg_a = __shfl(meta, i0a * 16 + 12);
    const int r0_a  = __shfl(meta, i0a * 16 + 13);

    // ---- Phase 0a: per-(node,slot) partial alpha = S_src + ae, packed half (lanes<48) ----
    if (lane < 48 && s0a < deg_a) {
        const int li = w * 4 + i0a;
        const unsigned* sru = (const unsigned*)(Sin + (size_t)sn_a * 20);      // 5 u32 = 10 halfs
        const unsigned* aer = (const unsigned*)ae + (size_t)(r0_a + s0a) * 5;
        unsigned* aSrow = (unsigned*)&Gl[li * 648];
#pragma unroll
        for (int p = 0; p < 5; ++p) {
            __half2 sv = __builtin_bit_cast(__half2, sru[p]);
            __half2 ev = __builtin_bit_cast(__half2, aer[p]);
            aSrow[s0a * 5 + p] = __builtin_bit_cast(unsigned, __hadd2(sv, ev));
        }
    }
    __builtin_amdgcn_wave_barrier();

    // ---- Phase 0b shuffles: ALL lanes active (clamped indices) ----
    const int i0b = (lane < 40) ? (lane / 10) : 0;
    const int h_b = (lane < 40) ? (lane - i0b * 10) : 0;
    const int deg_b = __shfl(meta, i0b * 16 + 12);
    const int r0_b  = __shfl(meta, i0b * 16 + 13);

    // ---- Phase 0b: per-(node,head) softmax over aS (lanes<40, wave-private) ----
    if (lane < 40) {
        const int i0 = i0b, h = h_b;
        const int li = w * 4 + i0;
        const int n = nb4 + i0;
        const int deg = deg_b, r0 = r0_b;
        const float sd = (float)Sin[(size_t)n * 20 + 10 + h];
        const __half* aSrowh = (const __half*)&Gl[li * 648];
        float aL[12];
        float m = -1e30f;
#pragma unroll
        for (int s = 0; s < 12; ++s) {
            float a = -1e30f;
            if (s < deg) {
                a = (float)aSrowh[s * 10 + h] + sd;
                a = (a > 0.f) ? a : 0.2f * a;
                m = fmaxf(m, a);
            }
            aL[s] = a;
        }
        if (deg > 12) {                       // extremely rare
            for (int s = 12; s < deg; ++s) {
                int sn = scsr[r0 + s];
                float a = (float)Sin[(size_t)sn * 20 + h] + sd + (float)ae[(size_t)(r0 + s) * NHD + h];
                a = (a > 0.f) ? a : 0.2f * a;
                wraw[(size_t)(r0 + s) * NHD + h] = (__half)a;
                m = fmaxf(m, a);
            }
        }
        float z = 0.f;
#pragma unroll
        for (int s = 0; s < 12; ++s) {
            float e = (s < deg) ? __expf(aL[s] - m) : 0.f;
            aL[s] = e;
            z += e;
        }
        for (int s = 12; s < deg; ++s) {
            float e = __expf((float)wraw[(size_t)(r0 + s) * NHD + h] - m);
            wraw[(size_t)(r0 + s) * NHD + h] = (__half)e;
            z += e;
        }
        float zi = 1.f / z;
#pragma unroll
        for (int s = 0; s < 12; ++s)
            wL[li * 120 + s * 10 + h] = (__half)(aL[s] * zi);
        for (int s = 12; s < deg; ++s)
            wraw[(size_t)(r0 + s) * NHD + h] =
                (__half)((float)wraw[(size_t)(r0 + s) * NHD + h] * zi);
    }
    __builtin_amdgcn_wave_barrier();

    // ---- Phase A: readlane broadcasts -> packed-f16 FMA ----
    const unsigned* wLu = (const unsigned*)wL;
    int wfu[4];
#pragma unroll
    for (int i = 0; i < 4; ++i)
        wfu[i] = (int)wLu[(w * 4 + i) * 60 + (lane & 31)];
#pragma unroll
    for (int i = 0; i < 4; ++i) {
        const int li = w * 4 + i;
        const int deg = RLI(meta, i * 16 + 12);
        const int r0  = RLI(meta, i * 16 + 13);
        __half2 g[5];
#pragma unroll
        for (int p = 0; p < 5; ++p) g[p] = __half2{(__half)0.f, (__half)0.f};
#pragma unroll
        for (int j = 0; j < 6; ++j) {
            __half2 hvd = __half2half2(hv[i][j]);
#pragma unroll
            for (int p = 0; p < 5; ++p)
                g[p] = __hfma2(RLH2(wfu[i], j * 5 + p), hvd, g[p]);
        }
        if (deg > 6) {
            // chunk 1: slots 6..11 — weights from LDS, hv2 prefetched upfront
            {
                int w2 = (lane < 30) ? (int)wLu[li * 60 + 30 + lane] : 0;
#pragma unroll
                for (int j = 0; j < 6; ++j) {
                    __half2 hvd = __half2half2(hv2[i][j]);
#pragma unroll
                    for (int p = 0; p < 5; ++p)
                        g[p] = __hfma2(RLH2(w2, j * 5 + p), hvd, g[p]);
                }
            }
            // chunks >= 12: very rare, via scsr + wraw
            for (int c0 = 12; c0 < deg; c0 += 6) {
                const int rem = deg - c0;
                int w2 = (lane < 30 && (lane / 5) < rem)
                         ? (int)wrawu[(size_t)(r0 + c0) * 5 + lane] : 0;
                int s2 = (lane < 6 && c0 + lane < deg) ? scsr[r0 + c0 + lane] : 0;
                __half hv3[6];
#pragma unroll
                for (int j = 0; j < 6; ++j) {
                    int sv = RLI(s2, j);
                    hv3[j] = hinh[(size_t)sv * DH + lane];
                }
#pragma unroll
                for (int j = 0; j < 6; ++j) {
                    __half2 hvd = __half2half2(hv3[j]);
#pragma unroll
                    for (int p = 0; p < 5; ++p)
                        g[p] = __hfma2(RLH2(w2, j * 5 + p), hvd, g[p]);
                }
            }
        }
        // write G row: G[li][k*10+q], lane=k -> 5 packed dwords
        const int base = li * 648 + lane * 10;
#pragma unroll
        for (int p = 0; p < 5; ++p) {
            float f0 = __low2float(g[p]), f1 = __high2float(g[p]);
            unsigned u = (unsigned)f2bf(f0) | ((unsigned)f2bf(f1) << 16);
            *(unsigned*)&Gl[base + 2 * p] = u;
        }
    }
    __syncthreads();

    // ---- Phase B: xc = G @ B, one 16x16 col-tile per wave, K=640; BtP coalesced ----
    const int la = lane & 15, lb = lane >> 4;
    v4f acc = {0.f, 0.f, 0.f, 0.f};
    const unsigned short* bp = BtP + (size_t)w * 20 * 512;
#pragma unroll 5
    for (int t = 0; t < 20; ++t) {
        v8s av = *(const v8s*)&Gl[la * 648 + t * 32 + lb * 8];
        v8s bv = *(const v8s*)&bp[t * 512 + lane * 8];
        acc = MF(av, bv, acc);
    }
    __syncthreads();      // Gl reads done; epilogue reuses Gl as bf16 h-tile

    // ---- epilogue: bias + BN + gelu + residual (f16 h); stash hout tile (bf16) in LDS ----
    unsigned short* hlb = Gl;           // [16][72] bf16 (alias)
    const int f = w * 16 + la;
    const float bi = bias[f], gm = gam[f], bt_ = bet[f], mu = mean[f];
    const float iv = rsqrtf(var[f] + 1e-5f);
#pragma unroll
    for (int r = 0; r < 4; ++r) {
        const int local = lb * 4 + r;
        const int n = blk * 16 + local;
        float hvold = (float)hinh[(size_t)n * DH + f];
        float v = acc[r] + bi;
        v = (v - mu) * gm * iv + bt_;
        v = 0.5f * v * (1.0f + erff(v * 0.70710678118654752f));
        float hnew = hvold + v;
        houth[(size_t)n * DH + f] = (__half)hnew;
        hlb[local * 72 + f] = f2bf(hnew);
    }

    // ---- fused next-layer scores: S[16][20] via MFMA on 2 waves ----
    if (do_s) {
        __syncthreads();
        if (w < 2) {
            v4f sa = {0.f, 0.f, 0.f, 0.f};
#pragma unroll
            for (int t = 0; t < 2; ++t) {
                v8s av = *(const v8s*)&hlb[la * 72 + t * 32 + lb * 8];
                v8s bv = *(const v8s*)&WcB[(size_t)(w * 64 + lane) * 16 + t * 8];
                sa = MF(av, bv, sa);
            }
#pragma unroll
            for (int r = 0; r < 4; ++r) {
                const int n = blk * 16 + lb * 4 + r;
                if (w == 0) Sout[(size_t)n * 20 + la] = (__half)sa[r];
                else if (la < 4) Sout[(size_t)n * 20 + 16 + la] = (__half)sa[r];
            }
        }
    }
}

// ---------------- readout: out[g] = (segsum(hh)[g] @ W_out + cnt*b_out) / max(cnt,1) ----------------
__global__ __launch_bounds__(256) void k_gout(const __half* __restrict__ hh,
        const float* __restrict__ W, const float* __restrict__ b,
        const int* __restrict__ grp, float* __restrict__ out) {
    __shared__ float Wl[DH * DOUTC];  // 32 KB
    __shared__ float hl[4][DH];
    __shared__ float cl[4];
    for (int i = threadIdx.x; i < DH * DOUTC; i += 256) Wl[i] = W[i];
    int w = threadIdx.x >> 6, lane = threadIdx.x & 63;
    int g = blockIdx.x * 4 + w;
    int r0 = grp[g], r1 = grp[g + 1];
    float s = 0.f;
    for (int n = r0; n < r1; ++n) s += (float)hh[(size_t)n * DH + lane];
    hl[w][lane] = s;
    if (lane == 0) cl[w] = (float)(r1 - r0);
    __syncthreads();
    for (int idx = threadIdx.x; idx < 4 * DOUTC; idx += 256) {
        int gi = idx >> 7, c = idx & 127;
        float cnt = cl[gi];
        float inv = 1.f / fmaxf(cnt, 1.f);
        float acc = cnt * b[c];
        const float* hr = hl[gi];
#pragma unroll 16
        for (int k = 0; k < DH; ++k) acc += hr[k] * Wl[k * DOUTC + c];
        out[(size_t)(blockIdx.x * 4 + gi) * DOUTC + c] = acc * inv;
    }
}

// ---------------- launcher ----------------
extern "C" void kernel_launch(void* const* d_in, const int* in_sizes, int n_in,
                              void* d_out, int out_size, void* d_ws, size_t ws_size,
                              hipStream_t stream) {
    const float* x        = (const float*)d_in[0];
    const float* edge_attr= (const float*)d_in[1];
    const float* W_emb    = (const float*)d_in[2];
    const float* b_emb    = (const float*)d_in[3];
    const float* Ws       = (const float*)d_in[4];
    const float* att_src  = (const float*)d_in[5];
    const float* att_dst  = (const float*)d_in[6];
    const float* att_edge = (const float*)d_in[7];
    const float* W_edge   = (const float*)d_in[8];
    const float* bias     = (const float*)d_in[9];
    const float* bn_gamma = (const float*)d_in[10];
    const float* bn_beta  = (const float*)d_in[11];
    const float* bn_mean  = (const float*)d_in[12];
    const float* bn_var   = (const float*)d_in[13];
    const float* W_out    = (const float*)d_in[14];
    const float* b_out    = (const float*)d_in[15];
    const int*   srcp     = (const int*)d_in[16];
    const int*   dstp     = srcp + NE;
    const int*   batch    = (const int*)d_in[17];
    float* out = (float*)d_out;

    char* wsb = (char*)d_ws;
    size_t off = 0;
    auto alloc = [&](size_t bytes) -> void* {
        void* p = (void*)(wsb + off);
        off += (bytes + 255) & ~(size_t)255;
        return p;
    };
    __half* hh0   = (__half*)alloc((size_t)NN * DH * 2);
    __half* hh1   = (__half*)alloc((size_t)NN * DH * 2);
    __half* S0    = (__half*)alloc((size_t)NN * 20 * 2);
    __half* S1    = (__half*)alloc((size_t)NN * 20 * 2);
    __half* wraw  = (__half*)alloc((size_t)E2 * NHD * 2);
    __half* aeAll = (__half*)alloc((size_t)NL * E2 * NHD * 2);
    float*  loop  = (float*)alloc((size_t)NN * DE * 4);
    int*    cnt   = (int*)alloc((size_t)NN * 4);
    int*    rp    = (int*)alloc((size_t)(NN + 1) * 4);
    int*    cursor= (int*)alloc((size_t)NN * 4);
    int*    eidx  = (int*)alloc((size_t)E2 * 4);
    int*    scsr  = (int*)alloc((size_t)E2 * 4);
    int*    snl12 = (int*)alloc((size_t)NN * 16 * 4);
    int*    bsum  = (int*)alloc((size_t)SCAN_NB * 4);
    int*    grp   = (int*)alloc((size_t)(NG + 1) * 4);
    float*  WeT   = (float*)alloc((size_t)NL * 160 * 4);
    unsigned short* BtP = (unsigned short*)alloc((size_t)NL * 40960 * 2);
    unsigned short* WcB = (unsigned short*)alloc((size_t)NL * 2048 * 2);
    unsigned short* BH  = (unsigned short*)alloc((size_t)DH * 64 * 2);
    unsigned short* BL  = (unsigned short*)alloc((size_t)DH * 64 * 2);

    // constants + cnt zero (no CSR deps) first
    k_prep<<<(N_PRE + 255) / 256, 256, 0, stream>>>(
        Ws, att_src, att_dst, W_edge, att_edge, W_emb, BtP, WcB, BH, BL, WeT, cnt);

    // preprocessing: CSR + merged metadata/self-loop/graph-ptr pass
    k_cnt<<<(NE + 255) / 256, 256, 0, stream>>>(dstp, cnt);
    k_scan_a<<<SCAN_NB, SCAN_B, 0, stream>>>(cnt, bsum);
    k_scan_c<<<SCAN_NB, SCAN_B, 0, stream>>>(cnt, bsum, rp, cursor);
    k_csr_fill<<<(E2 + 255) / 256, 256, 0, stream>>>(srcp, dstp, rp, cursor, eidx, scsr);
    k_misc<<<(NN * 18 + 255) / 256, 256, 0, stream>>>(rp, scsr, eidx, cnt, edge_attr,
                                                      batch, snl12, grp, loop);

    // merged: embedding MFMA + layer-0 scores | a_e dots for all layers
    k_embae<<<EMB_BLOCKS + AE_BLOCKS, 256, 0, stream>>>(
        x, BH, BL, b_emb, WcB, hh0, S0, edge_attr, loop, WeT, eidx, aeAll);

    __half* hhb[2] = {hh0, hh1};
    __half* Sb[2]  = {S0, S1};
    for (int l = 0; l < NL; ++l) {
        __half* hinh  = hhb[l & 1];
        __half* houth = hhb[(l + 1) & 1];
        __half* Sin   = Sb[l & 1];
        __half* Sout  = Sb[(l + 1) & 1];
        k_layer<<<NN / 16, 256, 0, stream>>>(
            Sin, aeAll + (size_t)l * E2 * NHD, wraw, snl12, scsr, hinh,
            BtP + (size_t)l * 40960,
            WcB + (size_t)(l + 1 < NL ? l + 1 : 0) * 2048,
            (l + 1 < NL) ? 1 : 0, Sout,
            bias + l * DH, bn_gamma + l * DH, bn_beta + l * DH,
            bn_mean + l * DH, bn_var + l * DH, houth);
    }
    __half* hfinh = hhb[NL & 1];

    // readout (f16 h shadow)
    k_gout<<<NG / 4, 256, 0, stream>>>(hfinh, W_out, b_out, grp, out);
}

// Round 23
// 181.910 us; speedup vs baseline: 1.1202x; 1.0015x over previous
//
#include <hip/hip_runtime.h>
#include <hip/hip_fp16.h>
#include <math.h>

// ---------------- problem constants ----------------
constexpr int NN   = 50000;          // nodes
constexpr int NE   = 150000;         // edges
constexpr int DIN  = 48;
constexpr int DH   = 64;
constexpr int DE   = 16;
constexpr int NHD  = 10;             // heads
constexpr int NL   = 3;              // layers
constexpr int DOUTC= 128;
constexpr int NG   = 4096;           // graphs
constexpr int E2   = NE + NN;        // edges incl self loops (200000)
constexpr int SCAN_B  = 256;
constexpr int SCAN_NB = (NN + SCAN_B - 1) / SCAN_B;   // 196

typedef __bf16 v8bf __attribute__((ext_vector_type(8)));
typedef short  v8s  __attribute__((ext_vector_type(8)));
typedef float  v4f  __attribute__((ext_vector_type(4)));

__device__ inline unsigned short f2bf(float f) {
    unsigned u = __builtin_bit_cast(unsigned, f);
    unsigned r = (u + 0x7FFFu + ((u >> 16) & 1u)) >> 16;
    return (unsigned short)r;
}

__device__ inline v4f MF(v8s a, v8s b, v4f c) {
    return __builtin_amdgcn_mfma_f32_16x16x32_bf16(
        __builtin_bit_cast(v8bf, a), __builtin_bit_cast(v8bf, b), c, 0, 0, 0);
}
__device__ inline v4f MFB(v8bf a, v8s b, v4f c) {
    return __builtin_amdgcn_mfma_f32_16x16x32_bf16(
        a, __builtin_bit_cast(v8bf, b), c, 0, 0, 0);
}

// broadcast from a compile-time lane (no LDS)
#define RLI(v, l) __builtin_amdgcn_readlane((v), (l))
#define RLH2(v, l) __builtin_bit_cast(__half2, __builtin_amdgcn_readlane(__builtin_bit_cast(int, (v)), (l)))

// ---------------- preprocessing ----------------
__global__ void k_cnt(const int* __restrict__ dst, int* __restrict__ cnt) {
    int e = blockIdx.x * blockDim.x + threadIdx.x;
    if (e < NE) atomicAdd(&cnt[dst[e]], 1);
}

__global__ void k_scan_a(const int* __restrict__ cnt, int* __restrict__ bsum) {
    __shared__ int s[SCAN_B];
    int i = blockIdx.x * SCAN_B + threadIdx.x;
    s[threadIdx.x] = (i < NN) ? (cnt[i] + 1) : 0;   // +1 = self loop
    __syncthreads();
    for (int off = SCAN_B / 2; off > 0; off >>= 1) {
        if (threadIdx.x < off) s[threadIdx.x] += s[threadIdx.x + off];
        __syncthreads();
    }
    if (threadIdx.x == 0) bsum[blockIdx.x] = s[0];
}

// block offset computed in-kernel; also zeroes cursor
__global__ void k_scan_c(const int* __restrict__ cnt, const int* __restrict__ bsum,
                         int* __restrict__ rp, int* __restrict__ cursor) {
    __shared__ int s[SCAN_B];
    __shared__ int boff_s;
    const int t = threadIdx.x;
    int partial = (t < SCAN_NB && t < blockIdx.x) ? bsum[t] : 0;
    s[t] = partial;
    __syncthreads();
    for (int off = SCAN_B / 2; off > 0; off >>= 1) {
        if (t < off) s[t] += s[t + off];
        __syncthreads();
    }
    if (t == 0) boff_s = s[0];
    __syncthreads();
    const int boff = boff_s;
    __syncthreads();
    int i = blockIdx.x * SCAN_B + t;
    if (i < NN) cursor[i] = 0;
    int v = (i < NN) ? (cnt[i] + 1) : 0;
    s[t] = v;
    __syncthreads();
    for (int off = 1; off < SCAN_B; off <<= 1) {
        int tv = (t >= off) ? s[t - off] : 0;
        __syncthreads();
        s[t] += tv;
        __syncthreads();
    }
    if (i < NN) {
        int excl = boff + s[t] - v;
        rp[i] = excl;
        if (i == NN - 1) rp[NN] = excl + v;
    }
}

__global__ void k_csr_fill(const int* __restrict__ src, const int* __restrict__ dst,
                           const int* __restrict__ rp, int* __restrict__ cursor,
                           int* __restrict__ eidx, int* __restrict__ scsr) {
    int e = blockIdx.x * blockDim.x + threadIdx.x;
    if (e >= E2) return;
    int d  = (e < NE) ? dst[e] : (e - NE);
    int sn = (e < NE) ? src[e] : d;
    int pos = atomicAdd(&cursor[d], 1);
    int s = rp[d] + pos;
    eidx[s] = e; scsr[s] = sn;
}

// merged: snl12 metadata + graph row ptrs + self-loop attrs (per-node, vectorized)
__global__ void k_misc(const int* __restrict__ rp, const int* __restrict__ scsr,
                       const int* __restrict__ eidx, const int* __restrict__ cnt,
                       const float* __restrict__ ea, const int* __restrict__ batch,
                       int* __restrict__ snl12, int* __restrict__ grp,
                       float* __restrict__ loop) {
    int tid = blockIdx.x * blockDim.x + threadIdx.x;
    if (tid < NN * 16) {
        int n = tid >> 4, j = tid & 15;
        int r0 = rp[n], deg = rp[n + 1] - r0;
        int v;
        if (j < 12)      v = (j < deg) ? scsr[r0 + j] : 0;
        else if (j == 12) v = deg;
        else if (j == 13) v = r0;
        else             v = 0;
        snl12[tid] = v;
    } else if (tid < NN * 17) {
        int n = tid - NN * 16;
        int b = batch[n];
        int pb = (n == 0) ? -1 : batch[n - 1];
        for (int g = pb + 1; g <= b; ++g) grp[g] = n;
        if (n == NN - 1) for (int g = b + 1; g <= NG; ++g) grp[g] = NN;
    } else if (tid < NN * 18) {
        int n = tid - NN * 17;
        int r0 = rp[n], r1 = rp[n + 1];
        float4 a0 = {0.f,0.f,0.f,0.f}, a1 = {0.f,0.f,0.f,0.f};
        float4 a2 = {0.f,0.f,0.f,0.f}, a3 = {0.f,0.f,0.f,0.f};
        for (int q = r0; q < r1; ++q) {
            int eid = eidx[q];
            if (eid < NE) {
                const float* ar = ea + (size_t)eid * DE;
                float4 b0 = *(const float4*)(ar + 0);
                float4 b1 = *(const float4*)(ar + 4);
                float4 b2 = *(const float4*)(ar + 8);
                float4 b3 = *(const float4*)(ar + 12);
                a0.x+=b0.x; a0.y+=b0.y; a0.z+=b0.z; a0.w+=b0.w;
                a1.x+=b1.x; a1.y+=b1.y; a1.z+=b1.z; a1.w+=b1.w;
                a2.x+=b2.x; a2.y+=b2.y; a2.z+=b2.z; a2.w+=b2.w;
                a3.x+=b3.x; a3.y+=b3.y; a3.z+=b3.z; a3.w+=b3.w;
            }
        }
        int c = cnt[n];
        float inv = (c > 1) ? (1.0f / (float)c) : 1.0f;
        a0.x*=inv; a0.y*=inv; a0.z*=inv; a0.w*=inv;
        a1.x*=inv; a1.y*=inv; a1.z*=inv; a1.w*=inv;
        a2.x*=inv; a2.y*=inv; a2.z*=inv; a2.w*=inv;
        a3.x*=inv; a3.y*=inv; a3.z*=inv; a3.w*=inv;
        float* lp = loop + (size_t)n * DE;
        *(float4*)(lp + 0)  = a0;
        *(float4*)(lp + 4)  = a1;
        *(float4*)(lp + 8)  = a2;
        *(float4*)(lp + 12) = a3;
    }
}

// ---------------- merged constant prep: BtP + WcB(direct dot) + W_emb hi/lo + WeT + cnt zero ----------------
constexpr int N_BTP = NL * 40960;      // 122880
constexpr int N_WCB = NL * 2048;       // 6144
constexpr int N_EMB = DH * 64;         // 4096
constexpr int N_WET = NL * DE * NHD;   // 480
constexpr int N_PRE = N_BTP + N_WCB + N_EMB + N_WET + NN;
__global__ void k_prep(const float* __restrict__ Ws, const float* __restrict__ asrc,
                       const float* __restrict__ adst, const float* __restrict__ We_in,
                       const float* __restrict__ aedge, const float* __restrict__ Wemb,
                       unsigned short* __restrict__ BtP, unsigned short* __restrict__ WcB,
                       unsigned short* __restrict__ BH, unsigned short* __restrict__ BL,
                       float* __restrict__ WeT, int* __restrict__ cnt) {
    int tid = blockIdx.x * blockDim.x + threadIdx.x;
    if (tid < N_BTP) {
        int e  = tid & 7;
        int ln = (tid >> 3) & 63;
        int t  = (tid >> 9) % 20;
        int ct = (tid / 10240) & 3;
        int l  = tid / 40960;
        int f = ct * 16 + (ln & 15);
        int kidx = t * 32 + (ln >> 4) * 8 + e;
        int k = kidx / 10, q = kidx - 10 * (kidx / 10);
        float v = Ws[((size_t)l * DH + k) * 640 + q * 64 + f] * 0.1f;
        BtP[tid] = f2bf(v);
    } else if (tid < N_BTP + N_WCB) {
        int r0 = tid - N_BTP;
        int l = r0 / 2048, r = r0 % 2048;
        int tile = r / 1024, rr = r % 1024;
        int ln = rr / 16, idx = rr % 16;
        int t2 = idx / 8, e = idx % 8;
        int k = t2 * 32 + (ln >> 4) * 8 + e;
        int jc = ln & 15;
        int j = tile * 16 + jc;
        float v = 0.f;
        if (j < 20) {
            int hh = j % NHD;
            const float* a = ((j < NHD) ? asrc : adst) + (size_t)l * NHD * DH + hh * DH;
            const float* w = Ws + ((size_t)l * DH + k) * 640 + hh * DH;
            float s = 0.f;
#pragma unroll
            for (int f = 0; f < DH; ++f) s += w[f] * a[f];
            v = s;
        }
        WcB[r0] = f2bf(v);
    } else if (tid < N_BTP + N_WCB + N_EMB) {
        int r0 = tid - N_BTP - N_WCB;
        int c = r0 >> 6, k = r0 & 63;
        float v = (k < DIN) ? Wemb[(size_t)k * DH + c] : 0.f;
        __bf16 hi = (__bf16)v;
        BH[r0] = __builtin_bit_cast(unsigned short, hi);
        BL[r0] = __builtin_bit_cast(unsigned short, (__bf16)(v - (float)hi));
    } else if (tid < N_BTP + N_WCB + N_EMB + N_WET) {
        int t3 = tid - N_BTP - N_WCB - N_EMB;
        int l = t3 / 160, rr = t3 % 160;
        int hh = rr / 16, d = rr % 16;
        const float* a = aedge + (size_t)l * NHD * DH + hh * DH;
        const float* w = We_in + ((size_t)l * DE + d) * 640 + hh * DH;
        float s = 0.f;
#pragma unroll
        for (int f = 0; f < DH; ++f) s += w[f] * a[f];
        WeT[l * 160 + hh * 16 + d] = s;
    } else if (tid < N_PRE) {
        cnt[tid - (N_BTP + N_WCB + N_EMB + N_WET)] = 0;
    }
}

// ---------------- merged: embedding MFMA + layer-0 scores (blocks < EMB_BLOCKS) | a_e dots (rest) ----
constexpr int EMB_BLOCKS = (NN + 63) / 64;                 // 782
constexpr int AE_BLOCKS  = (E2 * NHD + 255) / 256;         // 7813
__global__ __launch_bounds__(256) void k_embae(const float* __restrict__ x,
        const unsigned short* __restrict__ BH, const unsigned short* __restrict__ BL,
        const float* __restrict__ bemb, const unsigned short* __restrict__ WcB,
        __half* __restrict__ hh, __half* __restrict__ S,
        const float* __restrict__ ea, const float* __restrict__ loop,
        const float* __restrict__ WeT, const int* __restrict__ eidx,
        __half* __restrict__ aeAll) {
    if (blockIdx.x >= EMB_BLOCKS) {
        // ---- a_e per (slot, head), all 3 layers ----
        int tid = (blockIdx.x - EMB_BLOCKS) * 256 + threadIdx.x;
        if (tid >= E2 * NHD) return;
        int s = tid / NHD, h = tid - (tid / NHD) * NHD;
        int eid = eidx[s];
        const float* ar = (eid < NE) ? (ea + (size_t)eid * DE) : (loop + (size_t)(eid - NE) * DE);
        float4 a0 = *(const float4*)(ar + 0);
        float4 a1 = *(const float4*)(ar + 4);
        float4 a2 = *(const float4*)(ar + 8);
        float4 a3 = *(const float4*)(ar + 12);
#pragma unroll
        for (int l = 0; l < NL; ++l) {
            const float* wt = WeT + l * 160 + h * 16;
            float4 w0 = *(const float4*)(wt + 0);
            float4 w1 = *(const float4*)(wt + 4);
            float4 w2 = *(const float4*)(wt + 8);
            float4 w3 = *(const float4*)(wt + 12);
            float v = a0.x*w0.x + a0.y*w0.y + a0.z*w0.z + a0.w*w0.w
                    + a1.x*w1.x + a1.y*w1.y + a1.z*w1.z + a1.w*w1.w
                    + a2.x*w2.x + a2.y*w2.y + a2.z*w2.z + a2.w*w2.w
                    + a3.x*w3.x + a3.y*w3.y + a3.z*w3.z + a3.w*w3.w;
            aeAll[(size_t)l * E2 * NHD + tid] = (__half)v;
        }
        return;
    }
    // ---- embedding via MFMA (hi/lo split) + fused layer-0 scores ----
    __shared__ __align__(16) unsigned short hlb[4][16 * 72];
    const int tid = threadIdx.x;
    const int w = tid >> 6, lane = tid & 63;
    const int la = lane & 15, lb = lane >> 4;
    const int rowbase = blockIdx.x * 64 + w * 16;
    const int nA = rowbase + la;

    v8bf ah[2], al[2];
#pragma unroll
    for (int ks = 0; ks < 2; ++ks) {
        const int k0 = ks * 32 + lb * 8;
        float xv[8];
        if (nA < NN && k0 < DIN) {
            const float* xp = x + (size_t)nA * DIN + k0;
            float4 v0 = *(const float4*)xp;
            float4 v1 = *(const float4*)(xp + 4);
            xv[0]=v0.x; xv[1]=v0.y; xv[2]=v0.z; xv[3]=v0.w;
            xv[4]=v1.x; xv[5]=v1.y; xv[6]=v1.z; xv[7]=v1.w;
        } else {
#pragma unroll
            for (int e = 0; e < 8; ++e) xv[e] = 0.f;
        }
#pragma unroll
        for (int e = 0; e < 8; ++e) {
            __bf16 hi = (__bf16)xv[e];
            ah[ks][e] = hi;
            al[ks][e] = (__bf16)(xv[e] - (float)hi);
        }
    }
    v4f acc[4];
#pragma unroll
    for (int ct = 0; ct < 4; ++ct) acc[ct] = (v4f){0.f, 0.f, 0.f, 0.f};
#pragma unroll
    for (int ct = 0; ct < 4; ++ct) {
#pragma unroll
        for (int ks = 0; ks < 2; ++ks) {
            const int boff = (ct * 16 + la) * 64 + ks * 32 + lb * 8;
            v8s bh = *(const v8s*)&BH[boff];
            v8s bl = *(const v8s*)&BL[boff];
            acc[ct] = MFB(ah[ks], bh, acc[ct]);
            acc[ct] = MFB(al[ks], bh, acc[ct]);
            acc[ct] = MFB(ah[ks], bl, acc[ct]);
        }
    }
#pragma unroll
    for (int ct = 0; ct < 4; ++ct) {
        const int c = ct * 16 + la;
        const float bi = bemb[c];
#pragma unroll
        for (int r = 0; r < 4; ++r) {
            const int row = lb * 4 + r;
            const int n = rowbase + row;
            float v = acc[ct][r] + bi;
            if (n < NN) hh[(size_t)n * DH + c] = (__half)v;
            hlb[w][row * 72 + c] = f2bf(v);
        }
    }
    __syncthreads();
    v4f s0 = {0.f,0.f,0.f,0.f}, s1 = {0.f,0.f,0.f,0.f};
#pragma unroll
    for (int t = 0; t < 2; ++t) {
        v8s av = *(const v8s*)&hlb[w][la * 72 + t * 32 + lb * 8];
        v8s b0 = *(const v8s*)&WcB[(size_t)(lane) * 16 + t * 8];
        v8s b1 = *(const v8s*)&WcB[(size_t)(64 + lane) * 16 + t * 8];
        s0 = MF(av, b0, s0);
        s1 = MF(av, b1, s1);
    }
#pragma unroll
    for (int r = 0; r < 4; ++r) {
        const int n = rowbase + lb * 4 + r;
        if (n < NN) {
            S[(size_t)n * 20 + la] = (__half)s0[r];
            if (la < 4) S[(size_t)n * 20 + 16 + la] = (__half)s1[r];
        }
    }
}

// ---------------- fused layer: wave-private softmax (0a/0b) -> pk-f16 agg -> MFMA -> epilogue -> next-S ----
// S is f16. wL is aliased into Gl row tails (halfs 480..599 of each row): consumed (dataflow-ordered)
// before that row's G store, so no extra LDS -> 20736 B total -> 7 blocks/CU.
__global__ __launch_bounds__(256) void k_layer(
        const __half* __restrict__ Sin, const __half* __restrict__ ae,
        __half* __restrict__ wraw,
        const int* __restrict__ snl12, const int* __restrict__ scsr,
        const __half* __restrict__ hinh,
        const unsigned short* __restrict__ BtP, const unsigned short* __restrict__ WcB,
        int do_s, __half* __restrict__ Sout,
        const float* __restrict__ bias, const float* __restrict__ gam,
        const float* __restrict__ bet, const float* __restrict__ mean,
        const float* __restrict__ var, __half* __restrict__ houth) {
    __shared__ __align__(16) unsigned short Gl[16 * 648];   // 20736 B (rows wave-private until Phase B)

    const int tid = threadIdx.x;
    const int w = tid >> 6, lane = tid & 63;
    const int blk = blockIdx.x;
    const int nb4 = blk * 16 + w * 4;
    const unsigned* wrawu = (const unsigned*)wraw;
    const unsigned* GlU = (const unsigned*)Gl;
    constexpr int WOFF = 240;   // dword offset of wL region within a row (half 480)

    // ---- meta: 4 nodes x 16 ints maps exactly onto 64 lanes ----
    const int meta = snl12[nb4 * 16 + lane];

    // ---- issue Phase-A gathers early (latency hides under Phase 0); prefetch slots 6-11 too ----
    __half hv[4][6];
    __half hv2[4][6];
#pragma unroll
    for (int i = 0; i < 4; ++i) {
#pragma unroll
        for (int j = 0; j < 6; ++j) {
            int sv = RLI(meta, i * 16 + j);
            hv[i][j] = hinh[(size_t)sv * DH + lane];
        }
        const int deg_i = RLI(meta, i * 16 + 12);   // wave-uniform
        if (deg_i > 6) {
#pragma unroll
            for (int j = 0; j < 6; ++j) {
                int sv = RLI(meta, i * 16 + 6 + j);
                hv2[i][j] = hinh[(size_t)sv * DH + lane];
            }
        }
    }

    // ---- Phase 0a shuffles: ALL lanes active (clamped indices) ----
    const int i0a = (lane < 48) ? (lane / 12) : 0;
    const int s0a = (lane < 48) ? (lane - i0a * 12) : 0;
    const int sn_a  = __shfl(meta, i0a * 16 + s0a);
    const int deg_a = __shfl(meta, i0a * 16 + 12);
    const int r0_a  = __shfl(meta, i0a * 16 + 13);

    // ---- Phase 0a: per-(node,slot) partial alpha = S_src + ae, packed half (lanes<48) ----
    if (lane < 48 && s0a < deg_a) {
        const int li = w * 4 + i0a;
        const unsigned* sru = (const unsigned*)(Sin + (size_t)sn_a * 20);      // 5 u32 = 10 halfs
        const unsigned* aer = (const unsigned*)ae + (size_t)(r0_a + s0a) * 5;
        unsigned* aSrow = (unsigned*)&Gl[li * 648];
#pragma unroll
        for (int p = 0; p < 5; ++p) {
            __half2 sv = __builtin_bit_cast(__half2, sru[p]);
            __half2 ev = __builtin_bit_cast(__half2, aer[p]);
            aSrow[s0a * 5 + p] = __builtin_bit_cast(unsigned, __hadd2(sv, ev));
        }
    }
    __builtin_amdgcn_wave_barrier();

    // ---- Phase 0b shuffles: ALL lanes active (clamped indices) ----
    const int i0b = (lane < 40) ? (lane / 10) : 0;
    const int h_b = (lane < 40) ? (lane - i0b * 10) : 0;
    const int deg_b = __shfl(meta, i0b * 16 + 12);
    const int r0_b  = __shfl(meta, i0b * 16 + 13);

    // ---- Phase 0b: per-(node,head) softmax over aS (lanes<40, wave-private) ----
    if (lane < 40) {
        const int i0 = i0b, h = h_b;
        const int li = w * 4 + i0;
        const int n = nb4 + i0;
        const int deg = deg_b, r0 = r0_b;
        const float sd = (float)Sin[(size_t)n * 20 + 10 + h];
        const __half* aSrowh = (const __half*)&Gl[li * 648];
        float aL[12];
        float m = -1e30f;
#pragma unroll
        for (int s = 0; s < 12; ++s) {
            float a = -1e30f;
            if (s < deg) {
                a = (float)aSrowh[s * 10 + h] + sd;
                a = (a > 0.f) ? a : 0.2f * a;
                m = fmaxf(m, a);
            }
            aL[s] = a;
        }
        if (deg > 12) {                       // extremely rare
            for (int s = 12; s < deg; ++s) {
                int sn = scsr[r0 + s];
                float a = (float)Sin[(size_t)sn * 20 + h] + sd + (float)ae[(size_t)(r0 + s) * NHD + h];
                a = (a > 0.f) ? a : 0.2f * a;
                wraw[(size_t)(r0 + s) * NHD + h] = (__half)a;
                m = fmaxf(m, a);
            }
        }
        float z = 0.f;
#pragma unroll
        for (int s = 0; s < 12; ++s) {
            float e = (s < deg) ? __expf(aL[s] - m) : 0.f;
            aL[s] = e;
            z += e;
        }
        for (int s = 12; s < deg; ++s) {
            float e = __expf((float)wraw[(size_t)(r0 + s) * NHD + h] - m);
            wraw[(size_t)(r0 + s) * NHD + h] = (__half)e;
            z += e;
        }
        float zi = 1.f / z;
        __half* wLrow = (__half*)&Gl[li * 648 + 480];   // wL region: halfs 480..599 of row li
#pragma unroll
        for (int s = 0; s < 12; ++s)
            wLrow[s * 10 + h] = (__half)(aL[s] * zi);
        for (int s = 12; s < deg; ++s)
            wraw[(size_t)(r0 + s) * NHD + h] =
                (__half)((float)wraw[(size_t)(r0 + s) * NHD + h] * zi);
    }
    __builtin_amdgcn_wave_barrier();

    // ---- Phase A: readlane broadcasts -> packed-f16 FMA ----
    int wfu[4];
#pragma unroll
    for (int i = 0; i < 4; ++i)
        wfu[i] = (int)GlU[(w * 4 + i) * 324 + WOFF + (lane & 31)];
#pragma unroll
    for (int i = 0; i < 4; ++i) {
        const int li = w * 4 + i;
        const int deg = RLI(meta, i * 16 + 12);
        const int r0  = RLI(meta, i * 16 + 13);
        __half2 g[5];
#pragma unroll
        for (int p = 0; p < 5; ++p) g[p] = __half2{(__half)0.f, (__half)0.f};
#pragma unroll
        for (int j = 0; j < 6; ++j) {
            __half2 hvd = __half2half2(hv[i][j]);
#pragma unroll
            for (int p = 0; p < 5; ++p)
                g[p] = __hfma2(RLH2(wfu[i], j * 5 + p), hvd, g[p]);
        }
        if (deg > 6) {
            // chunk 1: slots 6..11 — weights from wL region (read before this row's G store; dataflow-ordered)
            {
                int w2 = (lane < 30) ? (int)GlU[li * 324 + WOFF + 30 + lane] : 0;
#pragma unroll
                for (int j = 0; j < 6; ++j) {
                    __half2 hvd = __half2half2(hv2[i][j]);
#pragma unroll
                    for (int p = 0; p < 5; ++p)
                        g[p] = __hfma2(RLH2(w2, j * 5 + p), hvd, g[p]);
                }
            }
            // chunks >= 12: very rare, via scsr + wraw
            for (int c0 = 12; c0 < deg; c0 += 6) {
                const int rem = deg - c0;
                int w2 = (lane < 30 && (lane / 5) < rem)
                         ? (int)wrawu[(size_t)(r0 + c0) * 5 + lane] : 0;
                int s2 = (lane < 6 && c0 + lane < deg) ? scsr[r0 + c0 + lane] : 0;
                __half hv3[6];
#pragma unroll
                for (int j = 0; j < 6; ++j) {
                    int sv = RLI(s2, j);
                    hv3[j] = hinh[(size_t)sv * DH + lane];
                }
#pragma unroll
                for (int j = 0; j < 6; ++j) {
                    __half2 hvd = __half2half2(hv3[j]);
#pragma unroll
                    for (int p = 0; p < 5; ++p)
                        g[p] = __hfma2(RLH2(w2, j * 5 + p), hvd, g[p]);
                }
            }
        }
        // write G row: G[li][k*10+q], lane=k -> 5 packed dwords (overwrites wL region of row li)
        const int base = li * 648 + lane * 10;
#pragma unroll
        for (int p = 0; p < 5; ++p) {
            float f0 = __low2float(g[p]), f1 = __high2float(g[p]);
            unsigned u = (unsigned)f2bf(f0) | ((unsigned)f2bf(f1) << 16);
            *(unsigned*)&Gl[base + 2 * p] = u;
        }
    }
    __syncthreads();

    // ---- Phase B: xc = G @ B, one 16x16 col-tile per wave, K=640; BtP coalesced ----
    const int la = lane & 15, lb = lane >> 4;
    v4f acc = {0.f, 0.f, 0.f, 0.f};
    const unsigned short* bp = BtP + (size_t)w * 20 * 512;
#pragma unroll 5
    for (int t = 0; t < 20; ++t) {
        v8s av = *(const v8s*)&Gl[la * 648 + t * 32 + lb * 8];
        v8s bv = *(const v8s*)&bp[t * 512 + lane * 8];
        acc = MF(av, bv, acc);
    }
    __syncthreads();      // Gl reads done; epilogue reuses Gl as bf16 h-tile

    // ---- epilogue: bias + BN + gelu + residual (f16 h); stash hout tile (bf16) in LDS ----
    unsigned short* hlb = Gl;           // [16][72] bf16 (alias)
    const int f = w * 16 + la;
    const float bi = bias[f], gm = gam[f], bt_ = bet[f], mu = mean[f];
    const float iv = rsqrtf(var[f] + 1e-5f);
#pragma unroll
    for (int r = 0; r < 4; ++r) {
        const int local = lb * 4 + r;
        const int n = blk * 16 + local;
        float hvold = (float)hinh[(size_t)n * DH + f];
        float v = acc[r] + bi;
        v = (v - mu) * gm * iv + bt_;
        v = 0.5f * v * (1.0f + erff(v * 0.70710678118654752f));
        float hnew = hvold + v;
        houth[(size_t)n * DH + f] = (__half)hnew;
        hlb[local * 72 + f] = f2bf(hnew);
    }

    // ---- fused next-layer scores: S[16][20] via MFMA on 2 waves ----
    if (do_s) {
        __syncthreads();
        if (w < 2) {
            v4f sa = {0.f, 0.f, 0.f, 0.f};
#pragma unroll
            for (int t = 0; t < 2; ++t) {
                v8s av = *(const v8s*)&hlb[la * 72 + t * 32 + lb * 8];
                v8s bv = *(const v8s*)&WcB[(size_t)(w * 64 + lane) * 16 + t * 8];
                sa = MF(av, bv, sa);
            }
#pragma unroll
            for (int r = 0; r < 4; ++r) {
                const int n = blk * 16 + lb * 4 + r;
                if (w == 0) Sout[(size_t)n * 20 + la] = (__half)sa[r];
                else if (la < 4) Sout[(size_t)n * 20 + 16 + la] = (__half)sa[r];
            }
        }
    }
}

// ---------------- readout: out[g] = (segsum(hh)[g] @ W_out + cnt*b_out) / max(cnt,1) ----------------
__global__ __launch_bounds__(256) void k_gout(const __half* __restrict__ hh,
        const float* __restrict__ W, const float* __restrict__ b,
        const int* __restrict__ grp, float* __restrict__ out) {
    __shared__ float Wl[DH * DOUTC];  // 32 KB
    __shared__ float hl[4][DH];
    __shared__ float cl[4];
    for (int i = threadIdx.x; i < DH * DOUTC; i += 256) Wl[i] = W[i];
    int w = threadIdx.x >> 6, lane = threadIdx.x & 63;
    int g = blockIdx.x * 4 + w;
    int r0 = grp[g], r1 = grp[g + 1];
    float s = 0.f;
    for (int n = r0; n < r1; ++n) s += (float)hh[(size_t)n * DH + lane];
    hl[w][lane] = s;
    if (lane == 0) cl[w] = (float)(r1 - r0);
    __syncthreads();
    for (int idx = threadIdx.x; idx < 4 * DOUTC; idx += 256) {
        int gi = idx >> 7, c = idx & 127;
        float cnt = cl[gi];
        float inv = 1.f / fmaxf(cnt, 1.f);
        float acc = cnt * b[c];
        const float* hr = hl[gi];
#pragma unroll 16
        for (int k = 0; k < DH; ++k) acc += hr[k] * Wl[k * DOUTC + c];
        out[(size_t)(blockIdx.x * 4 + gi) * DOUTC + c] = acc * inv;
    }
}

// ---------------- launcher ----------------
extern "C" void kernel_launch(void* const* d_in, const int* in_sizes, int n_in,
                              void* d_out, int out_size, void* d_ws, size_t ws_size,
                              hipStream_t stream) {
    const float* x        = (const float*)d_in[0];
    const float* edge_attr= (const float*)d_in[1];
    const float* W_emb    = (const float*)d_in[2];
    const float* b_emb    = (const float*)d_in[3];
    const float* Ws       = (const float*)d_in[4];
    const float* att_src  = (const float*)d_in[5];
    const float* att_dst  = (const float*)d_in[6];
    const float* att_edge = (const float*)d_in[7];
    const float* W_edge   = (const float*)d_in[8];
    const float* bias     = (const float*)d_in[9];
    const float* bn_gamma = (const float*)d_in[10];
    const float* bn_beta  = (const float*)d_in[11];
    const float* bn_mean  = (const float*)d_in[12];
    const float* bn_var   = (const float*)d_in[13];
    const float* W_out    = (const float*)d_in[14];
    const float* b_out    = (const float*)d_in[15];
    const int*   srcp     = (const int*)d_in[16];
    const int*   dstp     = srcp + NE;
    const int*   batch    = (const int*)d_in[17];
    float* out = (float*)d_out;

    char* wsb = (char*)d_ws;
    size_t off = 0;
    auto alloc = [&](size_t bytes) -> void* {
        void* p = (void*)(wsb + off);
        off += (bytes + 255) & ~(size_t)255;
        return p;
    };
    __half* hh0   = (__half*)alloc((size_t)NN * DH * 2);
    __half* hh1   = (__half*)alloc((size_t)NN * DH * 2);
    __half* S0    = (__half*)alloc((size_t)NN * 20 * 2);
    __half* S1    = (__half*)alloc((size_t)NN * 20 * 2);
    __half* wraw  = (__half*)alloc((size_t)E2 * NHD * 2);
    __half* aeAll = (__half*)alloc((size_t)NL * E2 * NHD * 2);
    float*  loop  = (float*)alloc((size_t)NN * DE * 4);
    int*    cnt   = (int*)alloc((size_t)NN * 4);
    int*    rp    = (int*)alloc((size_t)(NN + 1) * 4);
    int*    cursor= (int*)alloc((size_t)NN * 4);
    int*    eidx  = (int*)alloc((size_t)E2 * 4);
    int*    scsr  = (int*)alloc((size_t)E2 * 4);
    int*    snl12 = (int*)alloc((size_t)NN * 16 * 4);
    int*    bsum  = (int*)alloc((size_t)SCAN_NB * 4);
    int*    grp   = (int*)alloc((size_t)(NG + 1) * 4);
    float*  WeT   = (float*)alloc((size_t)NL * 160 * 4);
    unsigned short* BtP = (unsigned short*)alloc((size_t)NL * 40960 * 2);
    unsigned short* WcB = (unsigned short*)alloc((size_t)NL * 2048 * 2);
    unsigned short* BH  = (unsigned short*)alloc((size_t)DH * 64 * 2);
    unsigned short* BL  = (unsigned short*)alloc((size_t)DH * 64 * 2);

    // constants + cnt zero (no CSR deps) first
    k_prep<<<(N_PRE + 255) / 256, 256, 0, stream>>>(
        Ws, att_src, att_dst, W_edge, att_edge, W_emb, BtP, WcB, BH, BL, WeT, cnt);

    // preprocessing: CSR + merged metadata/self-loop/graph-ptr pass
    k_cnt<<<(NE + 255) / 256, 256, 0, stream>>>(dstp, cnt);
    k_scan_a<<<SCAN_NB, SCAN_B, 0, stream>>>(cnt, bsum);
    k_scan_c<<<SCAN_NB, SCAN_B, 0, stream>>>(cnt, bsum, rp, cursor);
    k_csr_fill<<<(E2 + 255) / 256, 256, 0, stream>>>(srcp, dstp, rp, cursor, eidx, scsr);
    k_misc<<<(NN * 18 + 255) / 256, 256, 0, stream>>>(rp, scsr, eidx, cnt, edge_attr,
                                                      batch, snl12, grp, loop);

    // merged: embedding MFMA + layer-0 scores | a_e dots for all layers
    k_embae<<<EMB_BLOCKS + AE_BLOCKS, 256, 0, stream>>>(
        x, BH, BL, b_emb, WcB, hh0, S0, edge_attr, loop, WeT, eidx, aeAll);

    __half* hhb[2] = {hh0, hh1};
    __half* Sb[2]  = {S0, S1};
    for (int l = 0; l < NL; ++l) {
        __half* hinh  = hhb[l & 1];
        __half* houth = hhb[(l + 1) & 1];
        __half* Sin   = Sb[l & 1];
        __half* Sout  = Sb[(l + 1) & 1];
        k_layer<<<NN / 16, 256, 0, stream>>>(
            Sin, aeAll + (size_t)l * E2 * NHD, wraw, snl12, scsr, hinh,
            BtP + (size_t)l * 40960,
            WcB + (size_t)(l + 1 < NL ? l + 1 : 0) * 2048,
            (l + 1 < NL) ? 1 : 0, Sout,
            bias + l * DH, bn_gamma + l * DH, bn_beta + l * DH,
            bn_mean + l * DH, bn_var + l * DH, houth);
    }
    __half* hfinh = hhb[NL & 1];

    // readout (f16 h shadow)
    k_gout<<<NG / 4, 256, 0, stream>>>(hfinh, W_out, b_out, grp, out);
}